// Round 1
// baseline (26029.672 us; speedup 1.0000x reference)
//
#include <hip/hip_runtime.h>

#define Bb 8
#define C  64
#define Hh 128
#define Ww 128
#define HW (Hh * Ww)

// ---------------------------------------------------------------------------
// Dense conv (NCHW/OIHW), stride 1: out[b,oc,h,w] = bias[oc] +
//   sum_{c,ki,kj} x[b,c,h-PAD+ki*DIL, w-PAD+kj*DIL] * wgt[oc,c,ki,kj]
// One thread per output pixel; blockIdx.y = output channel. Weights for this
// oc staged in LDS (broadcast reads, no conflicts). x reads coalesced across w.
// ---------------------------------------------------------------------------
template <int K, int PAD, int DIL>
__global__ void offset_conv_kernel(const float* __restrict__ x,
                                   const float* __restrict__ wgt,
                                   const float* __restrict__ bias,
                                   float* __restrict__ out, int OC) {
    const int oc = blockIdx.y;
    __shared__ float wl[C * K * K];
    for (int i = threadIdx.x; i < C * K * K; i += 256)
        wl[i] = wgt[(size_t)oc * C * K * K + i];
    __syncthreads();

    const int p = blockIdx.x * 256 + threadIdx.x;  // pixel in [0, Bb*HW)
    const int b = p / HW;
    const int hw = p % HW;
    const int h = hw / Ww;
    const int w = hw % Ww;

    float acc = bias[oc];
    const float* xb = x + (size_t)b * C * HW;
    for (int ki = 0; ki < K; ++ki) {
        const int y = h - PAD + ki * DIL;
        if (y < 0 || y >= Hh) continue;
        for (int kj = 0; kj < K; ++kj) {
            const int xq = w - PAD + kj * DIL;
            if (xq < 0 || xq >= Ww) continue;
            const float* xp = xb + y * Ww + xq;
            const float* wp = wl + ki * K + kj;
            #pragma unroll 8
            for (int c = 0; c < C; ++c)
                acc = fmaf(xp[(size_t)c * HW], wp[c * K * K], acc);
        }
    }
    out[((size_t)b * OC + oc) * HW + hw] = acc;
}

// ---------------------------------------------------------------------------
// Deformable depthwise conv. off: [B, 2*K*K, H, W] (dy=ch 2t, dx=ch 2t+1).
// One thread per pixel, 16-channel chunk per blockIdx.y. Bilinear corner
// indices/weights computed once per tap, reused across 16 channels.
// Zero padding outside bounds (valid-masked weights, clamped indices).
// ---------------------------------------------------------------------------
template <int K, int PAD, int DIL>
__global__ void deform_dw_kernel(const float* __restrict__ x,
                                 const float* __restrict__ off,
                                 const float* __restrict__ dw,  // [C, K*K]
                                 float* __restrict__ out) {
    const int cbase = blockIdx.y * 16;
    __shared__ float dwl[16 * K * K];
    for (int i = threadIdx.x; i < 16 * K * K; i += 256) {
        const int ci = i / (K * K), t = i % (K * K);
        dwl[i] = dw[(size_t)(cbase + ci) * K * K + t];
    }
    __syncthreads();

    const int p = blockIdx.x * 256 + threadIdx.x;
    const int b = p / HW;
    const int hw = p % HW;
    const int h = hw / Ww;
    const int w = hw % Ww;

    float acc[16];
    #pragma unroll
    for (int i = 0; i < 16; ++i) acc[i] = 0.f;

    const float* xb = x + ((size_t)b * C + cbase) * HW;
    const float* ob = off + (size_t)b * (2 * K * K) * HW + hw;

    for (int t = 0; t < K * K; ++t) {
        const int ki = t / K, kj = t % K;
        const float dy = ob[(size_t)(2 * t) * HW];
        const float dx = ob[(size_t)(2 * t + 1) * HW];
        const float py = (float)(h - PAD + ki * DIL) + dy;
        const float px = (float)(w - PAD + kj * DIL) + dx;
        const float y0f = floorf(py), x0f = floorf(px);
        const float wy = py - y0f, wx = px - x0f;
        const int y0 = (int)y0f, x0 = (int)x0f;
        const int y1 = y0 + 1, x1 = x0 + 1;
        const float vy0 = (y0 >= 0 && y0 < Hh) ? 1.f : 0.f;
        const float vy1 = (y1 >= 0 && y1 < Hh) ? 1.f : 0.f;
        const float vx0 = (x0 >= 0 && x0 < Ww) ? 1.f : 0.f;
        const float vx1 = (x1 >= 0 && x1 < Ww) ? 1.f : 0.f;
        const int y0c = min(max(y0, 0), Hh - 1), y1c = min(max(y1, 0), Hh - 1);
        const int x0c = min(max(x0, 0), Ww - 1), x1c = min(max(x1, 0), Ww - 1);
        const float w00 = (1.f - wy) * (1.f - wx) * vy0 * vx0;
        const float w01 = (1.f - wy) * wx * vy0 * vx1;
        const float w10 = wy * (1.f - wx) * vy1 * vx0;
        const float w11 = wy * wx * vy1 * vx1;
        const int i00 = y0c * Ww + x0c, i01 = y0c * Ww + x1c;
        const int i10 = y1c * Ww + x0c, i11 = y1c * Ww + x1c;
        #pragma unroll 4
        for (int ci = 0; ci < 16; ++ci) {
            const float* xp = xb + (size_t)ci * HW;
            const float v = w00 * xp[i00] + w01 * xp[i01] +
                            w10 * xp[i10] + w11 * xp[i11];
            acc[ci] = fmaf(v, dwl[ci * K * K + t], acc[ci]);
        }
    }

    float* op = out + ((size_t)b * C + cbase) * HW + hw;
    #pragma unroll
    for (int ci = 0; ci < 16; ++ci) op[(size_t)ci * HW] = acc[ci];
}

// ---------------------------------------------------------------------------
// 1x1 conv (C->C) + bias, then out = x * attn. Thread per output element,
// blockIdx.y = output channel. Weights row in LDS.
// ---------------------------------------------------------------------------
__global__ void pw_mul_kernel(const float* __restrict__ attn,
                              const float* __restrict__ w1,  // [C,C]
                              const float* __restrict__ b1,
                              const float* __restrict__ x,
                              float* __restrict__ out) {
    const int o = blockIdx.y;
    __shared__ float wl[C];
    if (threadIdx.x < C) wl[threadIdx.x] = w1[(size_t)o * C + threadIdx.x];
    __syncthreads();

    const int p = blockIdx.x * 256 + threadIdx.x;
    const int b = p / HW;
    const int hw = p % HW;

    const float* ap = attn + (size_t)b * C * HW + hw;
    float acc = b1[o];
    #pragma unroll 8
    for (int c = 0; c < C; ++c) acc = fmaf(ap[(size_t)c * HW], wl[c], acc);

    const size_t oi = ((size_t)b * C + o) * HW + hw;
    out[oi] = x[oi] * acc;
}

extern "C" void kernel_launch(void* const* d_in, const int* in_sizes, int n_in,
                              void* d_out, int out_size, void* d_ws, size_t ws_size,
                              hipStream_t stream) {
    const float* x       = (const float*)d_in[0];
    const float* off0_w  = (const float*)d_in[1];
    const float* off0_b  = (const float*)d_in[2];
    const float* dw0_w   = (const float*)d_in[3];
    const float* off1_w  = (const float*)d_in[4];
    const float* off1_b  = (const float*)d_in[5];
    const float* dw1_w   = (const float*)d_in[6];
    const float* conv1_w = (const float*)d_in[7];
    const float* conv1_b = (const float*)d_in[8];
    float* out = (float*)d_out;

    // Workspace layout (floats): attn0 [B*C*HW], attn1 [B*C*HW],
    // offbuf [B*98*HW] (shared by off0 (50ch) then off1 (98ch)).
    float* attn0 = (float*)d_ws;
    float* attn1 = attn0 + (size_t)Bb * C * HW;
    float* offb  = attn1 + (size_t)Bb * C * HW;

    const dim3 blk(256);
    const int PXB = (Bb * HW) / 256;  // 512 pixel-blocks

    // Stage 1: off0 = conv5x5(x); attn0 = deform_dw(x, off0, dw0)
    offset_conv_kernel<5, 2, 1><<<dim3(PXB, 50), blk, 0, stream>>>(x, off0_w, off0_b, offb, 50);
    deform_dw_kernel<5, 2, 1><<<dim3(PXB, 4), blk, 0, stream>>>(x, offb, dw0_w, attn0);

    // Stage 2: off1 = conv7x7_d3(attn0); attn1 = deform_dw(attn0, off1, dw1)
    offset_conv_kernel<7, 9, 3><<<dim3(PXB, 98), blk, 0, stream>>>(attn0, off1_w, off1_b, offb, 98);
    deform_dw_kernel<7, 9, 3><<<dim3(PXB, 4), blk, 0, stream>>>(attn0, offb, dw1_w, attn1);

    // Stage 3: out = x * (conv1x1(attn1) + b)
    pw_mul_kernel<<<dim3(PXB, C), blk, 0, stream>>>(attn1, conv1_w, conv1_b, x, out);
}

// Round 2
// 1624.062 us; speedup vs baseline: 16.0275x; 16.0275x over previous
//
#include <hip/hip_runtime.h>

#define Bb 8
#define C  64
#define Hh 128
#define Ww 128
#define HW (Hh * Ww)

typedef __attribute__((ext_vector_type(8))) short b16x8;
typedef __attribute__((ext_vector_type(4))) float f32x4;

__device__ __forceinline__ ushort f2bf(float f) {
    union { float f; uint u; } x; x.f = f;
    uint r = (x.u + 0x7FFFu + ((x.u >> 16) & 1u)) >> 16;
    return (ushort)r;
}
__device__ __forceinline__ float bf2f(ushort u) {
    union { uint u; float f; } x; x.u = ((uint)u) << 16;
    return x.f;
}

// ---------------------------------------------------------------------------
// NCHW fp32 -> NHWC bf16 (c innermost), transposed through LDS for coalescing.
// Grid: B*H*(W/64) = 2048 blocks, 256 threads.
// ---------------------------------------------------------------------------
__global__ void pack_nhwc(const float* __restrict__ in, ushort* __restrict__ out) {
    __shared__ ushort t[64][65];
    const int bx = blockIdx.x;
    const int b = bx >> 8, rem = bx & 255, h = rem >> 1, w0 = (rem & 1) << 6;
    const int x = threadIdx.x, wl = x & 63, cs = x >> 6;
    const float* ip = in + (((size_t)b * 64) << 14) + (h << 7) + w0 + wl;
    #pragma unroll
    for (int i = 0; i < 16; ++i) {
        const int c = i * 4 + cs;
        t[wl][c] = f2bf(ip[(size_t)c << 14]);
    }
    __syncthreads();
    ushort* op = out + ((size_t)((b * Hh + h) * Ww + w0)) * 64 + wl;
    #pragma unroll
    for (int i = 0; i < 16; ++i) {
        const int w = i * 4 + cs;
        op[(size_t)w * 64] = t[w][wl];
    }
}

// ---------------------------------------------------------------------------
// Weight pack: OIHW fp32 [OC][64][K][K] -> [S][OCP][32] bf16, where
// slice s covers tap t=s>>1, c-half (s&1)*32; zero-pad oc in [OC,OCP).
// ---------------------------------------------------------------------------
__global__ void pack_w(const float* __restrict__ src, ushort* __restrict__ dst,
                       int OC, int OCP, int KK, int n) {
    const int idx = blockIdx.x * 256 + threadIdx.x;
    if (idx >= n) return;
    const int kk = idx & 31;
    const int oc = (idx >> 5) % OCP;
    const int s = idx / (32 * OCP);
    const int c = (s & 1) * 32 + kk;
    const int t = s >> 1;
    const float v = (oc < OC) ? src[((size_t)oc * 64 + c) * KK + t] : 0.f;
    dst[idx] = f2bf(v);
}

// ---------------------------------------------------------------------------
// Offset conv as MFMA implicit GEMM (bf16 in, fp32 acc, bf16 out NCHW).
// Block: 256 thr (4 waves), 64-pixel row segment, all OC tiles.
// LDS: [KR rows][WIDTH][64c] bf16, XOR-swizzled (cslot ^ widx&7) to kill the
// 128B-stride bank conflict on ds_read_b128. K rows staged in ceil(K/KR)
// phases to stay under 64KB. Reduction: slice = (tap, c-half of 32).
// ---------------------------------------------------------------------------
template<int K, int PAD, int DIL, int OC, int OCP, int KR>
__global__ __launch_bounds__(256, 2) void conv_mfma(
    const ushort* __restrict__ xp,   // NHWC bf16
    const ushort* __restrict__ wp,   // [2*K*K][OCP][32] bf16
    const float* __restrict__ bias,
    ushort* __restrict__ outp) {     // NCHW bf16 [B][OC][H][W]
    constexpr int WIDTH = 64 + (K - 1) * DIL;
    constexpr int NT = OCP / 16;          // oc tiles
    constexpr int TPW = (NT + 3) / 4;     // oc tiles per wave
    __shared__ __align__(16) ushort lds[KR * WIDTH * 64];

    const int bx = blockIdx.x;
    const int b = bx >> 8, rem = bx & 255, h = rem >> 1, w0 = (rem & 1) << 6;
    const int tid = threadIdx.x, lane = tid & 63, wid = tid >> 6;
    const int l15 = lane & 15, lg = lane >> 4;

    f32x4 acc[TPW][4] = {};

    const int nph = (K + KR - 1) / KR;
    for (int ph = 0; ph < nph; ++ph) {
        const int kr0 = ph * KR;
        const int krn = (K - kr0 < KR) ? (K - kr0) : KR;
        __syncthreads();
        const int chunks = krn * WIDTH * 8;
        for (int q = tid; q < chunks; q += 256) {
            const int ki = q / (WIDTH * 8);
            const int r2 = q - ki * (WIDTH * 8);
            const int widx = r2 >> 3, csl = r2 & 7;
            const int y = h - PAD + (kr0 + ki) * DIL;
            const int w = w0 - PAD + widx;
            uint4 v = make_uint4(0, 0, 0, 0);
            if ((unsigned)y < (unsigned)Hh && (unsigned)w < (unsigned)Ww)
                v = *(const uint4*)(xp + (((size_t)(b * Hh + y) * Ww + w) << 6) + (csl << 3));
            ((uint4*)lds)[(ki * WIDTH + widx) * 8 + (csl ^ (widx & 7))] = v;
        }
        __syncthreads();

        const int t0 = kr0 * K, t1 = (kr0 + krn) * K;
        for (int t = t0; t < t1; ++t) {
            const int ki = t / K - kr0;
            const int kj = t - (t / K) * K;
            const int s0 = 2 * t;
            b16x8 a[2][TPW];
            #pragma unroll
            for (int i = 0; i < TPW; ++i) {
                if (wid + 4 * i < NT) {
                    const int ot = wid + 4 * i;
                    const size_t abase = ((size_t)(ot * 16 + l15)) * 32 + lg * 8;
                    a[0][i] = *(const b16x8*)(wp + (size_t)s0 * (OCP * 32) + abase);
                    a[1][i] = *(const b16x8*)(wp + (size_t)(s0 + 1) * (OCP * 32) + abase);
                }
            }
            const int wbase = l15 + kj * DIL;
            int idx = (ki * WIDTH + wbase) * 8 + (lg ^ (wbase & 7));
            #pragma unroll
            for (int pt = 0; pt < 4; ++pt) {
                const b16x8 b0 = ((const b16x8*)lds)[idx];
                const b16x8 b1 = ((const b16x8*)lds)[idx ^ 4];
                #pragma unroll
                for (int i = 0; i < TPW; ++i) {
                    if (wid + 4 * i < NT) {
                        acc[i][pt] = __builtin_amdgcn_mfma_f32_16x16x32_bf16(a[0][i], b0, acc[i][pt], 0, 0, 0);
                        acc[i][pt] = __builtin_amdgcn_mfma_f32_16x16x32_bf16(a[1][i], b1, acc[i][pt], 0, 0, 0);
                    }
                }
                idx += 128;
            }
        }
    }

    // Epilogue: C/D layout col=lane&15 (pixel), row=(lane>>4)*4+reg (oc).
    const size_t obase = (((size_t)b * OC) << 14) + (h << 7) + w0;
    #pragma unroll
    for (int i = 0; i < TPW; ++i) {
        const int ot = wid + 4 * i;
        if (ot >= NT) continue;
        #pragma unroll
        for (int r = 0; r < 4; ++r) {
            const int oc = ot * 16 + lg * 4 + r;
            if (oc < OC) {
                const float bv = bias[oc];
                #pragma unroll
                for (int pt = 0; pt < 4; ++pt)
                    outp[obase + ((size_t)oc << 14) + pt * 16 + l15] = f2bf(acc[i][pt][r] + bv);
            }
        }
    }
}

// ---------------------------------------------------------------------------
// Deformable depthwise conv; offsets now bf16 NCHW. One thread per pixel,
// 16-channel chunk per blockIdx.y.
// ---------------------------------------------------------------------------
template <int K, int PAD, int DIL>
__global__ void deform_dw_kernel(const float* __restrict__ x,
                                 const ushort* __restrict__ off,
                                 const float* __restrict__ dw,  // [C, K*K]
                                 float* __restrict__ out) {
    const int cbase = blockIdx.y * 16;
    __shared__ float dwl[16 * K * K];
    for (int i = threadIdx.x; i < 16 * K * K; i += 256) {
        const int ci = i / (K * K), t = i % (K * K);
        dwl[i] = dw[(size_t)(cbase + ci) * K * K + t];
    }
    __syncthreads();

    const int p = blockIdx.x * 256 + threadIdx.x;
    const int b = p / HW;
    const int hw = p % HW;
    const int h = hw / Ww;
    const int w = hw % Ww;

    float acc[16];
    #pragma unroll
    for (int i = 0; i < 16; ++i) acc[i] = 0.f;

    const float* xb = x + ((size_t)b * C + cbase) * HW;
    const ushort* ob = off + (size_t)b * (2 * K * K) * HW + hw;

    for (int t = 0; t < K * K; ++t) {
        const int ki = t / K, kj = t % K;
        const float dy = bf2f(ob[(size_t)(2 * t) * HW]);
        const float dx = bf2f(ob[(size_t)(2 * t + 1) * HW]);
        const float py = (float)(h - PAD + ki * DIL) + dy;
        const float px = (float)(w - PAD + kj * DIL) + dx;
        const float y0f = floorf(py), x0f = floorf(px);
        const float wy = py - y0f, wx = px - x0f;
        const int y0 = (int)y0f, x0 = (int)x0f;
        const int y1 = y0 + 1, x1 = x0 + 1;
        const float vy0 = (y0 >= 0 && y0 < Hh) ? 1.f : 0.f;
        const float vy1 = (y1 >= 0 && y1 < Hh) ? 1.f : 0.f;
        const float vx0 = (x0 >= 0 && x0 < Ww) ? 1.f : 0.f;
        const float vx1 = (x1 >= 0 && x1 < Ww) ? 1.f : 0.f;
        const int y0c = min(max(y0, 0), Hh - 1), y1c = min(max(y1, 0), Hh - 1);
        const int x0c = min(max(x0, 0), Ww - 1), x1c = min(max(x1, 0), Ww - 1);
        const float w00 = (1.f - wy) * (1.f - wx) * vy0 * vx0;
        const float w01 = (1.f - wy) * wx * vy0 * vx1;
        const float w10 = wy * (1.f - wx) * vy1 * vx0;
        const float w11 = wy * wx * vy1 * vx1;
        const int i00 = y0c * Ww + x0c, i01 = y0c * Ww + x1c;
        const int i10 = y1c * Ww + x0c, i11 = y1c * Ww + x1c;
        #pragma unroll 4
        for (int ci = 0; ci < 16; ++ci) {
            const float* xpp = xb + (size_t)ci * HW;
            const float v = w00 * xpp[i00] + w01 * xpp[i01] +
                            w10 * xpp[i10] + w11 * xpp[i11];
            acc[ci] = fmaf(v, dwl[ci * K * K + t], acc[ci]);
        }
    }

    float* op = out + ((size_t)b * C + cbase) * HW + hw;
    #pragma unroll
    for (int ci = 0; ci < 16; ++ci) op[(size_t)ci * HW] = acc[ci];
}

// ---------------------------------------------------------------------------
// 1x1 conv (C->C) + bias, then out = x * attn.
// ---------------------------------------------------------------------------
__global__ void pw_mul_kernel(const float* __restrict__ attn,
                              const float* __restrict__ w1,
                              const float* __restrict__ b1,
                              const float* __restrict__ x,
                              float* __restrict__ out) {
    const int o = blockIdx.y;
    __shared__ float wl[C];
    if (threadIdx.x < C) wl[threadIdx.x] = w1[(size_t)o * C + threadIdx.x];
    __syncthreads();

    const int p = blockIdx.x * 256 + threadIdx.x;
    const int b = p / HW;
    const int hw = p % HW;

    const float* ap = attn + (size_t)b * C * HW + hw;
    float acc = b1[o];
    #pragma unroll 8
    for (int c = 0; c < C; ++c) acc = fmaf(ap[(size_t)c * HW], wl[c], acc);

    const size_t oi = ((size_t)b * C + o) * HW + hw;
    out[oi] = x[oi] * acc;
}

extern "C" void kernel_launch(void* const* d_in, const int* in_sizes, int n_in,
                              void* d_out, int out_size, void* d_ws, size_t ws_size,
                              hipStream_t stream) {
    const float* x       = (const float*)d_in[0];
    const float* off0_w  = (const float*)d_in[1];
    const float* off0_b  = (const float*)d_in[2];
    const float* dw0_w   = (const float*)d_in[3];
    const float* off1_w  = (const float*)d_in[4];
    const float* off1_b  = (const float*)d_in[5];
    const float* dw1_w   = (const float*)d_in[6];
    const float* conv1_w = (const float*)d_in[7];
    const float* conv1_b = (const float*)d_in[8];
    float* out = (float*)d_out;

    // Workspace: attn0 f32 (32MB) | attn1 f32 (32MB) | offb bf16 (25.7MB) |
    // xp bf16 NHWC (16.8MB) | wp0 (200KB) | wp1 (702KB)  => ~107 MB total.
    const size_t NCH = (size_t)Bb * C * HW;
    float* attn0 = (float*)d_ws;
    float* attn1 = attn0 + NCH;
    ushort* offb = (ushort*)(attn1 + NCH);
    ushort* xp   = offb + (size_t)Bb * 98 * HW;
    ushort* wp0  = xp + (size_t)Bb * HW * 64;
    ushort* wp1  = wp0 + 50 * 64 * 32;

    const dim3 blk(256);
    const int PXB = (Bb * HW) / 256;  // 512

    // Packs
    pack_nhwc<<<2048, blk, 0, stream>>>(x, xp);
    pack_w<<<(50 * 64 * 32 + 255) / 256, blk, 0, stream>>>(off0_w, wp0, 50, 64, 25, 50 * 64 * 32);
    pack_w<<<(98 * 112 * 32 + 255) / 256, blk, 0, stream>>>(off1_w, wp1, 98, 112, 49, 98 * 112 * 32);

    // Stage 1
    conv_mfma<5, 2, 1, 50, 64, 5><<<2048, blk, 0, stream>>>(xp, wp0, off0_b, offb);
    deform_dw_kernel<5, 2, 1><<<dim3(PXB, 4), blk, 0, stream>>>(x, offb, dw0_w, attn0);

    // Stage 2
    pack_nhwc<<<2048, blk, 0, stream>>>(attn0, xp);
    conv_mfma<7, 9, 3, 98, 112, 4><<<2048, blk, 0, stream>>>(xp, wp1, off1_b, offb);
    deform_dw_kernel<7, 9, 3><<<dim3(PXB, 4), blk, 0, stream>>>(attn0, offb, dw1_w, attn1);

    // Stage 3
    pw_mul_kernel<<<dim3(PXB, C), blk, 0, stream>>>(attn1, conv1_w, conv1_b, x, out);
}

// Round 3
// 442.414 us; speedup vs baseline: 58.8355x; 3.6709x over previous
//
#include <hip/hip_runtime.h>

#define Bb 8
#define C  64
#define Hh 128
#define Ww 128
#define HW (Hh * Ww)

typedef __attribute__((ext_vector_type(8))) short b16x8;
typedef __attribute__((ext_vector_type(4))) float f32x4;

__device__ __forceinline__ ushort f2bf(float f) {
    union { float f; uint u; } x; x.f = f;
    uint r = (x.u + 0x7FFFu + ((x.u >> 16) & 1u)) >> 16;
    return (ushort)r;
}
__device__ __forceinline__ float blo(uint u) {  // bf16 in low ushort
    union { uint u; float f; } x; x.u = u << 16; return x.f;
}
__device__ __forceinline__ float bhi(uint u) {  // bf16 in high ushort
    union { uint u; float f; } x; x.u = u & 0xffff0000u; return x.f;
}

// ---------------------------------------------------------------------------
// NCHW fp32 -> NHWC bf16 (c innermost), transposed through LDS.
// ---------------------------------------------------------------------------
__global__ void pack_nhwc(const float* __restrict__ in, ushort* __restrict__ out) {
    __shared__ ushort t[64][65];
    const int bx = blockIdx.x;
    const int b = bx >> 8, rem = bx & 255, h = rem >> 1, w0 = (rem & 1) << 6;
    const int x = threadIdx.x, wl = x & 63, cs = x >> 6;
    const float* ip = in + (((size_t)b * 64) << 14) + (h << 7) + w0 + wl;
    #pragma unroll
    for (int i = 0; i < 16; ++i) {
        const int c = i * 4 + cs;
        t[wl][c] = f2bf(ip[(size_t)c << 14]);
    }
    __syncthreads();
    ushort* op = out + ((size_t)((b * Hh + h) * Ww + w0)) * 64 + wl;
    #pragma unroll
    for (int i = 0; i < 16; ++i) {
        const int w = i * 4 + cs;
        op[(size_t)w * 64] = t[w][wl];
    }
}

// Weight pack: OIHW fp32 -> [S][OCP][32] bf16 (slice s: tap s>>1, c-half s&1).
__global__ void pack_w(const float* __restrict__ src, ushort* __restrict__ dst,
                       int OC, int OCP, int KK, int n) {
    const int idx = blockIdx.x * 256 + threadIdx.x;
    if (idx >= n) return;
    const int kk = idx & 31;
    const int oc = (idx >> 5) % OCP;
    const int s = idx / (32 * OCP);
    const int c = (s & 1) * 32 + kk;
    const int t = s >> 1;
    const float v = (oc < OC) ? src[((size_t)oc * 64 + c) * KK + t] : 0.f;
    dst[idx] = f2bf(v);
}

// Depthwise weight transpose: [C][KK] -> [KK][C] f32.
__global__ void pack_dwt(const float* __restrict__ src, float* __restrict__ dst, int KK) {
    const int i = blockIdx.x * 256 + threadIdx.x;
    if (i < KK * 64) {
        const int t = i >> 6, ch = i & 63;
        dst[i] = src[ch * KK + t];
    }
}

// ---------------------------------------------------------------------------
// Offset conv as MFMA implicit GEMM. Output: pixel-interleaved bf16
// [B*HW][S] (S = 2*K*K taps of (dy,dx)) via LDS transpose, coalesced store.
// ---------------------------------------------------------------------------
template<int K, int PAD, int DIL, int OCP, int KR>
__global__ __launch_bounds__(256, 2) void conv_mfma(
    const ushort* __restrict__ xp,   // NHWC bf16
    const ushort* __restrict__ wp,   // [2*K*K][OCP][32] bf16
    const float* __restrict__ bias,
    ushort* __restrict__ outp) {     // [B*HW][S] bf16
    constexpr int WIDTH = 64 + (K - 1) * DIL;
    constexpr int S = 2 * K * K;
    constexpr int NT = OCP / 16;
    constexpr int TPW = (NT + 3) / 4;
    __shared__ __align__(16) ushort lds[KR * WIDTH * 64];

    const int bx = blockIdx.x;
    const int b = bx >> 8, rem = bx & 255, h = rem >> 1, w0 = (rem & 1) << 6;
    const int tid = threadIdx.x, lane = tid & 63, wid = tid >> 6;
    const int l15 = lane & 15, lg = lane >> 4;

    f32x4 acc[TPW][4] = {};

    const int nph = (K + KR - 1) / KR;
    for (int ph = 0; ph < nph; ++ph) {
        const int kr0 = ph * KR;
        const int krn = (K - kr0 < KR) ? (K - kr0) : KR;
        __syncthreads();
        const int chunks = krn * WIDTH * 8;
        for (int q = tid; q < chunks; q += 256) {
            const int ki = q / (WIDTH * 8);
            const int r2 = q - ki * (WIDTH * 8);
            const int widx = r2 >> 3, csl = r2 & 7;
            const int y = h - PAD + (kr0 + ki) * DIL;
            const int w = w0 - PAD + widx;
            uint4 v = make_uint4(0, 0, 0, 0);
            if ((unsigned)y < (unsigned)Hh && (unsigned)w < (unsigned)Ww)
                v = *(const uint4*)(xp + (((size_t)(b * Hh + y) * Ww + w) << 6) + (csl << 3));
            ((uint4*)lds)[(ki * WIDTH + widx) * 8 + (csl ^ (widx & 7))] = v;
        }
        __syncthreads();

        const int t0 = kr0 * K, t1 = (kr0 + krn) * K;
        for (int t = t0; t < t1; ++t) {
            const int ki = t / K - kr0;
            const int kj = t - (t / K) * K;
            const int s0 = 2 * t;
            b16x8 a[2][TPW];
            #pragma unroll
            for (int i = 0; i < TPW; ++i) {
                if (wid + 4 * i < NT) {
                    const int ot = wid + 4 * i;
                    const size_t abase = ((size_t)(ot * 16 + l15)) * 32 + lg * 8;
                    a[0][i] = *(const b16x8*)(wp + (size_t)s0 * (OCP * 32) + abase);
                    a[1][i] = *(const b16x8*)(wp + (size_t)(s0 + 1) * (OCP * 32) + abase);
                }
            }
            const int wbase = l15 + kj * DIL;
            int idx = (ki * WIDTH + wbase) * 8 + (lg ^ (wbase & 7));
            #pragma unroll
            for (int pt = 0; pt < 4; ++pt) {
                const b16x8 b0 = ((const b16x8*)lds)[idx];
                const b16x8 b1 = ((const b16x8*)lds)[idx ^ 4];
                #pragma unroll
                for (int i = 0; i < TPW; ++i) {
                    if (wid + 4 * i < NT) {
                        acc[i][pt] = __builtin_amdgcn_mfma_f32_16x16x32_bf16(a[0][i], b0, acc[i][pt], 0, 0, 0);
                        acc[i][pt] = __builtin_amdgcn_mfma_f32_16x16x32_bf16(a[1][i], b1, acc[i][pt], 0, 0, 0);
                    }
                }
                idx += 128;
            }
        }
    }

    // Epilogue: acc -> LDS [64 pix][S], then flat coalesced copy to global.
    __syncthreads();
    ushort* lo_ = lds;
    #pragma unroll
    for (int i = 0; i < TPW; ++i) {
        const int ot = wid + 4 * i;
        if (ot >= NT) continue;
        #pragma unroll
        for (int r = 0; r < 4; ++r) {
            const int oc = ot * 16 + lg * 4 + r;
            if (oc < S) {
                const float bv = bias[oc];
                #pragma unroll
                for (int pt = 0; pt < 4; ++pt)
                    lo_[(pt * 16 + l15) * S + oc] = f2bf(acc[i][pt][r] + bv);
            }
        }
    }
    __syncthreads();
    const int nU = 64 * S / 2;
    uint* og = (uint*)outp + (size_t)((b * Hh + h) * Ww + w0) * (S / 2);
    for (int q = tid; q < nU; q += 256) og[q] = ((const uint*)lo_)[q];
}

// ---------------------------------------------------------------------------
// Deformable depthwise conv, NHWC. Thread = (pixel, 8-channel group).
// Offsets [pix][2KK] staged in LDS (flat coalesced); dw transposed [KK][64]
// staged in LDS. Corner reads: 16B uint4 per 8 channels, coalesced.
// ---------------------------------------------------------------------------
template <int K, int PAD, int DIL, bool OBF>
__global__ __launch_bounds__(256) void deform2(
    const ushort* __restrict__ xp,   // [B*HW][64] bf16
    const ushort* __restrict__ off,  // [B*HW][2KK] bf16
    const float* __restrict__ dwt,   // [KK][64] f32
    ushort* __restrict__ outb,       // [B*HW][64] bf16 (if OBF)
    float* __restrict__ outf) {      // [B*HW][64] f32  (if !OBF)
    constexpr int KK = K * K;
    __shared__ float dwl[KK * 64];
    __shared__ uint offl[32 * KK];
    const int tid = threadIdx.x;
    for (int i = tid; i < KK * 64; i += 256) dwl[i] = dwt[i];
    const int pix0 = blockIdx.x * 32;
    const uint* og = (const uint*)off + (size_t)pix0 * KK;
    for (int q = tid; q < 32 * KK; q += 256) offl[q] = og[q];
    __syncthreads();

    const int pl = tid >> 3, g = tid & 7;
    const int pix = pix0 + pl;
    const int b = pix >> 14, hw = pix & 16383, h = hw >> 7, w = hw & 127;
    const ushort* xb = xp + (((size_t)b) << 20);  // b*HW*64

    float acc[8] = {0.f, 0.f, 0.f, 0.f, 0.f, 0.f, 0.f, 0.f};

    for (int t = 0; t < KK; ++t) {
        const int ki = t / K, kj = t - ki * K;
        const uint od = offl[pl * KK + t];
        const float py = (float)(h - PAD + ki * DIL) + blo(od);
        const float px = (float)(w - PAD + kj * DIL) + bhi(od);
        const float y0f = floorf(py), x0f = floorf(px);
        const float wy = py - y0f, wx = px - x0f;
        const int y0 = (int)y0f, x0 = (int)x0f;
        const int y1 = y0 + 1, x1 = x0 + 1;
        const float m00 = ((unsigned)y0 < 128u && (unsigned)x0 < 128u) ? 1.f : 0.f;
        const float m01 = ((unsigned)y0 < 128u && (unsigned)x1 < 128u) ? 1.f : 0.f;
        const float m10 = ((unsigned)y1 < 128u && (unsigned)x0 < 128u) ? 1.f : 0.f;
        const float m11 = ((unsigned)y1 < 128u && (unsigned)x1 < 128u) ? 1.f : 0.f;
        const int y0c = min(max(y0, 0), 127), y1c = min(max(y1, 0), 127);
        const int x0c = min(max(x0, 0), 127), x1c = min(max(x1, 0), 127);
        const float w00 = (1.f - wy) * (1.f - wx) * m00;
        const float w01 = (1.f - wy) * wx * m01;
        const float w10 = wy * (1.f - wx) * m10;
        const float w11 = wy * wx * m11;
        const int gb = g << 3;
        const uint4 qa = *(const uint4*)(xb + (((y0c << 7) | x0c) << 6) + gb);
        const uint4 qb = *(const uint4*)(xb + (((y0c << 7) | x1c) << 6) + gb);
        const uint4 qc = *(const uint4*)(xb + (((y1c << 7) | x0c) << 6) + gb);
        const uint4 qd = *(const uint4*)(xb + (((y1c << 7) | x1c) << 6) + gb);
        const uint* A = (const uint*)&qa;
        const uint* Bv = (const uint*)&qb;
        const uint* Cv = (const uint*)&qc;
        const uint* D = (const uint*)&qd;
        const float* dp = dwl + (t << 6) + gb;
        #pragma unroll
        for (int j = 0; j < 4; ++j) {
            const float v0 = w00 * blo(A[j]) + w01 * blo(Bv[j]) + w10 * blo(Cv[j]) + w11 * blo(D[j]);
            const float v1 = w00 * bhi(A[j]) + w01 * bhi(Bv[j]) + w10 * bhi(Cv[j]) + w11 * bhi(D[j]);
            acc[2 * j]     = fmaf(v0, dp[2 * j], acc[2 * j]);
            acc[2 * j + 1] = fmaf(v1, dp[2 * j + 1], acc[2 * j + 1]);
        }
    }

    if (OBF) {
        uint o4[4];
        #pragma unroll
        for (int j = 0; j < 4; ++j)
            o4[j] = (uint)f2bf(acc[2 * j]) | ((uint)f2bf(acc[2 * j + 1]) << 16);
        *(uint4*)(outb + ((size_t)pix << 6) + (g << 3)) = *(uint4*)o4;
    } else {
        float4 f0 = {acc[0], acc[1], acc[2], acc[3]};
        float4 f1 = {acc[4], acc[5], acc[6], acc[7]};
        float* op = outf + ((size_t)pix << 6) + (g << 3);
        *(float4*)op = f0;
        *(float4*)(op + 4) = f1;
    }
}

// ---------------------------------------------------------------------------
// 1x1 conv + bias + u*attn. attn NHWC f32, x/out NCHW f32.
// ---------------------------------------------------------------------------
__global__ __launch_bounds__(256) void pw_mul2(
    const float* __restrict__ attn, const float* __restrict__ w1,
    const float* __restrict__ b1, const float* __restrict__ x,
    float* __restrict__ out) {
    __shared__ float wl[4096];
    __shared__ float bl[64];
    const int tid = threadIdx.x;
    for (int i = tid; i < 4096; i += 256) wl[i] = w1[i];
    if (tid < 64) bl[tid] = b1[tid];
    __syncthreads();
    const int p = blockIdx.x * 256 + tid;
    const int b = p >> 14, hw = p & 16383;
    float a[64];
    const float* ap = attn + (size_t)p * 64;
    #pragma unroll
    for (int i = 0; i < 16; ++i) *(float4*)&a[i * 4] = *(const float4*)(ap + i * 4);
    const size_t xb = ((size_t)b << 20) + hw;
    for (int oc = 0; oc < 64; ++oc) {
        float s = bl[oc];
        const float* wr = wl + oc * 64;
        #pragma unroll
        for (int c = 0; c < 64; c += 4) {
            const float4 wv = *(const float4*)(wr + c);
            s = fmaf(a[c], wv.x, s);
            s = fmaf(a[c + 1], wv.y, s);
            s = fmaf(a[c + 2], wv.z, s);
            s = fmaf(a[c + 3], wv.w, s);
        }
        const size_t oi = xb + ((size_t)oc << 14);
        out[oi] = x[oi] * s;
    }
}

extern "C" void kernel_launch(void* const* d_in, const int* in_sizes, int n_in,
                              void* d_out, int out_size, void* d_ws, size_t ws_size,
                              hipStream_t stream) {
    const float* x       = (const float*)d_in[0];
    const float* off0_w  = (const float*)d_in[1];
    const float* off0_b  = (const float*)d_in[2];
    const float* dw0_w   = (const float*)d_in[3];
    const float* off1_w  = (const float*)d_in[4];
    const float* off1_b  = (const float*)d_in[5];
    const float* dw1_w   = (const float*)d_in[6];
    const float* conv1_w = (const float*)d_in[7];
    const float* conv1_b = (const float*)d_in[8];
    float* out = (float*)d_out;

    // Workspace: xp bf16 NHWC (16.8M) | attn0b bf16 NHWC (16.8M) |
    // attn1f f32 NHWC (33.6M) | offb bf16 (25.7M) | wp0 | wp1 | dwt0 | dwt1
    const size_t NPX = (size_t)Bb * HW;
    ushort* xp     = (ushort*)d_ws;
    ushort* attn0b = xp + NPX * 64;
    float*  attn1f = (float*)(attn0b + NPX * 64);
    ushort* offb   = (ushort*)(attn1f + NPX * 64);
    ushort* wp0    = offb + NPX * 98;
    ushort* wp1    = wp0 + 50 * 64 * 32;
    float*  dwt0   = (float*)(wp1 + 98 * 112 * 32);
    float*  dwt1   = dwt0 + 25 * 64;

    const dim3 blk(256);

    pack_nhwc<<<2048, blk, 0, stream>>>(x, xp);
    pack_w<<<(50 * 64 * 32 + 255) / 256, blk, 0, stream>>>(off0_w, wp0, 50, 64, 25, 50 * 64 * 32);
    pack_w<<<(98 * 112 * 32 + 255) / 256, blk, 0, stream>>>(off1_w, wp1, 98, 112, 49, 98 * 112 * 32);
    pack_dwt<<<(25 * 64 + 255) / 256, blk, 0, stream>>>(dw0_w, dwt0, 25);
    pack_dwt<<<(49 * 64 + 255) / 256, blk, 0, stream>>>(dw1_w, dwt1, 49);

    // Stage 1
    conv_mfma<5, 2, 1, 64, 5><<<2048, blk, 0, stream>>>(xp, wp0, off0_b, offb);
    deform2<5, 2, 1, true><<<4096, blk, 0, stream>>>(xp, offb, dwt0, attn0b, nullptr);

    // Stage 2 (attn0b is already NHWC bf16 -> no repack)
    conv_mfma<7, 9, 3, 112, 4><<<2048, blk, 0, stream>>>(attn0b, wp1, off1_b, offb);
    deform2<7, 9, 3, false><<<4096, blk, 0, stream>>>(attn0b, offb, dwt1, nullptr, attn1f);

    // Stage 3
    pw_mul2<<<512, blk, 0, stream>>>(attn1f, conv1_w, conv1_b, x, out);
}

// Round 5
// 392.553 us; speedup vs baseline: 66.3088x; 1.1270x over previous
//
#include <hip/hip_runtime.h>

#define Bb 8
#define C  64
#define Hh 128
#define Ww 128
#define HW (Hh * Ww)

typedef __attribute__((ext_vector_type(8))) short b16x8;
typedef __attribute__((ext_vector_type(4))) float f32x4;
typedef __attribute__((ext_vector_type(2))) float f32x2;
typedef __fp16 fp16x2 __attribute__((ext_vector_type(2)));

__device__ __forceinline__ ushort f2bf(float f) {
    union { float f; uint u; } x; x.f = f;
    uint r = (x.u + 0x7FFFu + ((x.u >> 16) & 1u)) >> 16;
    return (ushort)r;
}
__device__ __forceinline__ float blo(uint u) {
    union { uint u; float f; } x; x.u = u << 16; return x.f;
}
__device__ __forceinline__ float bhi(uint u) {
    union { uint u; float f; } x; x.u = u & 0xffff0000u; return x.f;
}

// ---------------------------------------------------------------------------
// NCHW fp32 -> NHWC bf16 (c innermost), transposed through LDS.
// ---------------------------------------------------------------------------
__global__ void pack_nhwc(const float* __restrict__ in, ushort* __restrict__ out) {
    __shared__ ushort t[64][65];
    const int bx = blockIdx.x;
    const int b = bx >> 8, rem = bx & 255, h = rem >> 1, w0 = (rem & 1) << 6;
    const int x = threadIdx.x, wl = x & 63, cs = x >> 6;
    const float* ip = in + (((size_t)b * 64) << 14) + (h << 7) + w0 + wl;
    #pragma unroll
    for (int i = 0; i < 16; ++i) {
        const int c = i * 4 + cs;
        t[wl][c] = f2bf(ip[(size_t)c << 14]);
    }
    __syncthreads();
    ushort* op = out + ((size_t)((b * Hh + h) * Ww + w0)) * 64 + wl;
    #pragma unroll
    for (int i = 0; i < 16; ++i) {
        const int w = i * 4 + cs;
        op[(size_t)w * 64] = t[w][wl];
    }
}

// Weight pack: OIHW fp32 -> [S][OCP][32] bf16 (slice s: tap s>>1, c-half s&1).
__global__ void pack_w(const float* __restrict__ src, ushort* __restrict__ dst,
                       int OC, int OCP, int KK, int n) {
    const int idx = blockIdx.x * 256 + threadIdx.x;
    if (idx >= n) return;
    const int kk = idx & 31;
    const int oc = (idx >> 5) % OCP;
    const int s = idx / (32 * OCP);
    const int c = (s & 1) * 32 + kk;
    const int t = s >> 1;
    const float v = (oc < OC) ? src[((size_t)oc * 64 + c) * KK + t] : 0.f;
    dst[idx] = f2bf(v);
}

// Depthwise weight transpose: [C][KK] -> [KK][C] f32.
__global__ void pack_dwt(const float* __restrict__ src, float* __restrict__ dst, int KK) {
    const int i = blockIdx.x * 256 + threadIdx.x;
    if (i < KK * 64) {
        const int t = i >> 6, ch = i & 63;
        dst[i] = src[ch * KK + t];
    }
}

// ---------------------------------------------------------------------------
// Offset conv as MFMA implicit GEMM -> pixel-interleaved offsets [B*HW][S].
// ---------------------------------------------------------------------------
template<int K, int PAD, int DIL, int OCP, int KR>
__global__ __launch_bounds__(256, 2) void conv_mfma(
    const ushort* __restrict__ xp,
    const ushort* __restrict__ wp,
    const float* __restrict__ bias,
    ushort* __restrict__ outp) {
    constexpr int WIDTH = 64 + (K - 1) * DIL;
    constexpr int S = 2 * K * K;
    constexpr int NT = OCP / 16;
    constexpr int TPW = (NT + 3) / 4;
    __shared__ __align__(16) ushort lds[KR * WIDTH * 64];

    const int bx = blockIdx.x;
    const int b = bx >> 8, rem = bx & 255, h = rem >> 1, w0 = (rem & 1) << 6;
    const int tid = threadIdx.x, lane = tid & 63, wid = tid >> 6;
    const int l15 = lane & 15, lg = lane >> 4;

    f32x4 acc[TPW][4] = {};

    const int nph = (K + KR - 1) / KR;
    for (int ph = 0; ph < nph; ++ph) {
        const int kr0 = ph * KR;
        const int krn = (K - kr0 < KR) ? (K - kr0) : KR;
        __syncthreads();
        const int chunks = krn * WIDTH * 8;
        for (int q = tid; q < chunks; q += 256) {
            const int ki = q / (WIDTH * 8);
            const int r2 = q - ki * (WIDTH * 8);
            const int widx = r2 >> 3, csl = r2 & 7;
            const int y = h - PAD + (kr0 + ki) * DIL;
            const int w = w0 - PAD + widx;
            uint4 v = make_uint4(0, 0, 0, 0);
            if ((unsigned)y < (unsigned)Hh && (unsigned)w < (unsigned)Ww)
                v = *(const uint4*)(xp + (((size_t)(b * Hh + y) * Ww + w) << 6) + (csl << 3));
            ((uint4*)lds)[(ki * WIDTH + widx) * 8 + (csl ^ (widx & 7))] = v;
        }
        __syncthreads();

        const int t0 = kr0 * K, t1 = (kr0 + krn) * K;
        for (int t = t0; t < t1; ++t) {
            const int ki = t / K - kr0;
            const int kj = t - (t / K) * K;
            const int s0 = 2 * t;
            b16x8 a[2][TPW];
            #pragma unroll
            for (int i = 0; i < TPW; ++i) {
                if (wid + 4 * i < NT) {
                    const int ot = wid + 4 * i;
                    const size_t abase = ((size_t)(ot * 16 + l15)) * 32 + lg * 8;
                    a[0][i] = *(const b16x8*)(wp + (size_t)s0 * (OCP * 32) + abase);
                    a[1][i] = *(const b16x8*)(wp + (size_t)(s0 + 1) * (OCP * 32) + abase);
                }
            }
            const int wbase = l15 + kj * DIL;
            int idx = (ki * WIDTH + wbase) * 8 + (lg ^ (wbase & 7));
            #pragma unroll
            for (int pt = 0; pt < 4; ++pt) {
                const b16x8 b0 = ((const b16x8*)lds)[idx];
                const b16x8 b1 = ((const b16x8*)lds)[idx ^ 4];
                #pragma unroll
                for (int i = 0; i < TPW; ++i) {
                    if (wid + 4 * i < NT) {
                        acc[i][pt] = __builtin_amdgcn_mfma_f32_16x16x32_bf16(a[0][i], b0, acc[i][pt], 0, 0, 0);
                        acc[i][pt] = __builtin_amdgcn_mfma_f32_16x16x32_bf16(a[1][i], b1, acc[i][pt], 0, 0, 0);
                    }
                }
                idx += 128;
            }
        }
    }

    __syncthreads();
    ushort* lo_ = lds;
    #pragma unroll
    for (int i = 0; i < TPW; ++i) {
        const int ot = wid + 4 * i;
        if (ot >= NT) continue;
        #pragma unroll
        for (int r = 0; r < 4; ++r) {
            const int oc = ot * 16 + lg * 4 + r;
            if (oc < S) {
                const float bv = bias[oc];
                #pragma unroll
                for (int pt = 0; pt < 4; ++pt)
                    lo_[(pt * 16 + l15) * S + oc] = f2bf(acc[i][pt][r] + bv);
            }
        }
    }
    __syncthreads();
    const int nU = 64 * S / 2;
    uint* og = (uint*)outp + (size_t)((b * Hh + h) * Ww + w0) * (S / 2);
    for (int q = tid; q < nU; q += 256) og[q] = ((const uint*)lo_)[q];
}

// ---------------------------------------------------------------------------
// Deformable depthwise conv, NHWC bf16 in/out.
// Phase 1 (setup): 32 pix x KK taps over 256 threads -> LDS {packed corner
//   indices (i00|i11<<14), 4 bilinear weights as 2x f16x2}.
// Phase 2 (main): thread = (pixel, 8-ch group); per tap: 2 broadcast ds_reads,
//   4 coalesced uint4 corner loads, packed-f32 bilinear + depthwise FMA.
// ---------------------------------------------------------------------------
template <int K, int PAD, int DIL>
__global__ __launch_bounds__(256) void deform3(
    const ushort* __restrict__ xp,   // [B*HW][64] bf16
    const ushort* __restrict__ off,  // [B*HW][2KK] bf16
    const float* __restrict__ dwt,   // [KK][64] f32
    ushort* __restrict__ outb) {     // [B*HW][64] bf16
    constexpr int KK = K * K;
    __shared__ float dwl[KK * 64];
    __shared__ uint sIdx[32 * KK];
    __shared__ __align__(8) uint2 sW[32 * KK];
    const int tid = threadIdx.x;
    const int pix0 = blockIdx.x * 32;

    for (int i = tid; i < KK * 64; i += 256) dwl[i] = dwt[i];

    // --- setup phase ---
    const uint* og = (const uint*)off + (size_t)pix0 * KK;
    for (int q = tid; q < 32 * KK; q += 256) {
        const int pl2 = q / KK, t2 = q - pl2 * KK;
        const int pix = pix0 + pl2;
        const int h = (pix >> 7) & 127, w = pix & 127;
        const uint od = og[q];
        const int ki = t2 / K, kj = t2 - ki * K;
        const float py = (float)(h - PAD + ki * DIL) + blo(od);
        const float px = (float)(w - PAD + kj * DIL) + bhi(od);
        const float y0f = floorf(py), x0f = floorf(px);
        const float wy = py - y0f, wx = px - x0f;
        const int y0 = (int)y0f, x0 = (int)x0f;
        const int y1 = y0 + 1, x1 = x0 + 1;
        const float m00 = ((unsigned)y0 < 128u && (unsigned)x0 < 128u) ? 1.f : 0.f;
        const float m01 = ((unsigned)y0 < 128u && (unsigned)x1 < 128u) ? 1.f : 0.f;
        const float m10 = ((unsigned)y1 < 128u && (unsigned)x0 < 128u) ? 1.f : 0.f;
        const float m11 = ((unsigned)y1 < 128u && (unsigned)x1 < 128u) ? 1.f : 0.f;
        const int y0c = min(max(y0, 0), 127), y1c = min(max(y1, 0), 127);
        const int x0c = min(max(x0, 0), 127), x1c = min(max(x1, 0), 127);
        const float w00 = (1.f - wy) * (1.f - wx) * m00;
        const float w01 = (1.f - wy) * wx * m01;
        const float w10 = wy * (1.f - wx) * m10;
        const float w11 = wy * wx * m11;
        const int i00 = (y0c << 7) | x0c;
        const int i11 = (y1c << 7) | x1c;
        sIdx[q] = (uint)i00 | ((uint)i11 << 14);
        union { fp16x2 h2; uint u; } ua, ub;
        ua.h2 = __builtin_amdgcn_cvt_pkrtz(w00, w01);
        ub.h2 = __builtin_amdgcn_cvt_pkrtz(w10, w11);
        sW[q] = make_uint2(ua.u, ub.u);
    }
    __syncthreads();

    // --- main phase ---
    const int pl = tid >> 3, g = tid & 7;
    const int pix = pix0 + pl;
    const int b = pix >> 14;
    const int gb = g << 3;
    const ushort* xb = xp + (((size_t)b) << 20) + gb;

    f32x2 acc2[4] = {};

    for (int t = 0; t < KK; ++t) {
        const int sid = pl * KK + t;
        const uint id = sIdx[sid];
        const uint2 w4 = sW[sid];
        union { uint u; fp16x2 h2; } va, vb;
        va.u = w4.x; vb.u = w4.y;
        const float w00 = (float)va.h2.x, w01 = (float)va.h2.y;
        const float w10 = (float)vb.h2.x, w11 = (float)vb.h2.y;
        const int i00 = id & 16383;
        const int i11 = (id >> 14) & 16383;
        const int i01 = (i00 & ~127) | (i11 & 127);
        const int i10 = (i11 & ~127) | (i00 & 127);
        const uint4 qa = *(const uint4*)(xb + (i00 << 6));
        const uint4 qb = *(const uint4*)(xb + (i01 << 6));
        const uint4 qc = *(const uint4*)(xb + (i10 << 6));
        const uint4 qd = *(const uint4*)(xb + (i11 << 6));
        const uint* A = (const uint*)&qa;
        const uint* Bv = (const uint*)&qb;
        const uint* Cv = (const uint*)&qc;
        const uint* D = (const uint*)&qd;
        const f32x2* dp2 = (const f32x2*)(dwl + (t << 6) + gb);
        #pragma unroll
        for (int j = 0; j < 4; ++j) {
            f32x2 av = {blo(A[j]), bhi(A[j])};
            f32x2 bvv = {blo(Bv[j]), bhi(Bv[j])};
            f32x2 cv = {blo(Cv[j]), bhi(Cv[j])};
            f32x2 dv = {blo(D[j]), bhi(D[j])};
            f32x2 v = av * w00;
            v += bvv * w01;
            v += cv * w10;
            v += dv * w11;
            acc2[j] += v * dp2[j];
        }
    }

    uint o4[4];
    #pragma unroll
    for (int j = 0; j < 4; ++j)
        o4[j] = (uint)f2bf(acc2[j].x) | ((uint)f2bf(acc2[j].y) << 16);
    *(uint4*)(outb + ((size_t)pix << 6) + gb) = *(uint4*)o4;
}

// ---------------------------------------------------------------------------
// Fused 1x1 conv (MFMA) + bias + u*attn. attn NHWC bf16; x/out NCHW f32.
// ---------------------------------------------------------------------------
__global__ __launch_bounds__(256) void pw_mfma(
    const ushort* __restrict__ attn, const ushort* __restrict__ wp2,
    const float* __restrict__ b1, const float* __restrict__ x,
    float* __restrict__ out) {
    __shared__ __align__(16) ushort lds[64 * 64];
    const int tid = threadIdx.x, lane = tid & 63, wid = tid >> 6;
    const int l15 = lane & 15, lg = lane >> 4;
    const int pix0 = blockIdx.x << 6;

    const uint4* src = (const uint4*)(attn + ((size_t)pix0 << 6));
    for (int q = tid; q < 512; q += 256) {
        const int widx = q >> 3, csl = q & 7;
        ((uint4*)lds)[widx * 8 + (csl ^ (widx & 7))] = src[q];
    }
    __syncthreads();

    const b16x8 a0 = *(const b16x8*)(wp2 + ((size_t)(wid * 16 + l15)) * 32 + lg * 8);
    const b16x8 a1 = *(const b16x8*)(wp2 + ((size_t)(64 + wid * 16 + l15)) * 32 + lg * 8);
    f32x4 acc[4] = {};
    #pragma unroll
    for (int pt = 0; pt < 4; ++pt) {
        const int wb = pt * 16 + l15;
        const int idx = wb * 8 + (lg ^ (wb & 7));
        const b16x8 b0 = ((const b16x8*)lds)[idx];
        const b16x8 b1v = ((const b16x8*)lds)[idx ^ 4];
        acc[pt] = __builtin_amdgcn_mfma_f32_16x16x32_bf16(a0, b0, acc[pt], 0, 0, 0);
        acc[pt] = __builtin_amdgcn_mfma_f32_16x16x32_bf16(a1, b1v, acc[pt], 0, 0, 0);
    }

    const int b = pix0 >> 14, hw0 = pix0 & 16383;
    #pragma unroll
    for (int r = 0; r < 4; ++r) {
        const int oc = wid * 16 + lg * 4 + r;
        const float bv = b1[oc];
        const size_t base = (((size_t)b * 64 + oc) << 14) + hw0;
        #pragma unroll
        for (int pt = 0; pt < 4; ++pt) {
            const size_t oi = base + pt * 16 + l15;
            out[oi] = x[oi] * (acc[pt][r] + bv);
        }
    }
}

extern "C" void kernel_launch(void* const* d_in, const int* in_sizes, int n_in,
                              void* d_out, int out_size, void* d_ws, size_t ws_size,
                              hipStream_t stream) {
    const float* x       = (const float*)d_in[0];
    const float* off0_w  = (const float*)d_in[1];
    const float* off0_b  = (const float*)d_in[2];
    const float* dw0_w   = (const float*)d_in[3];
    const float* off1_w  = (const float*)d_in[4];
    const float* off1_b  = (const float*)d_in[5];
    const float* dw1_w   = (const float*)d_in[6];
    const float* conv1_w = (const float*)d_in[7];
    const float* conv1_b = (const float*)d_in[8];
    float* out = (float*)d_out;

    const size_t NPX = (size_t)Bb * HW;
    ushort* xp     = (ushort*)d_ws;
    ushort* attn0b = xp + NPX * 64;
    ushort* attn1b = attn0b + NPX * 64;
    ushort* offb   = attn1b + NPX * 64;
    ushort* wp0    = offb + NPX * 98;
    ushort* wp1    = wp0 + 50 * 64 * 32;
    ushort* wpP    = wp1 + 98 * 112 * 32;
    float*  dwt0   = (float*)(wpP + 2 * 64 * 32);
    float*  dwt1   = dwt0 + 25 * 64;

    const dim3 blk(256);

    pack_nhwc<<<2048, blk, 0, stream>>>(x, xp);
    pack_w<<<(50 * 64 * 32 + 255) / 256, blk, 0, stream>>>(off0_w, wp0, 50, 64, 25, 50 * 64 * 32);
    pack_w<<<(98 * 112 * 32 + 255) / 256, blk, 0, stream>>>(off1_w, wp1, 98, 112, 49, 98 * 112 * 32);
    pack_w<<<16, blk, 0, stream>>>(conv1_w, wpP, 64, 64, 1, 2 * 64 * 32);
    pack_dwt<<<(25 * 64 + 255) / 256, blk, 0, stream>>>(dw0_w, dwt0, 25);
    pack_dwt<<<(49 * 64 + 255) / 256, blk, 0, stream>>>(dw1_w, dwt1, 49);

    // Stage 1
    conv_mfma<5, 2, 1, 64, 5><<<2048, blk, 0, stream>>>(xp, wp0, off0_b, offb);
    deform3<5, 2, 1><<<4096, blk, 0, stream>>>(xp, offb, dwt0, attn0b);

    // Stage 2
    conv_mfma<7, 9, 3, 112, 4><<<2048, blk, 0, stream>>>(attn0b, wp1, off1_b, offb);
    deform3<7, 9, 3><<<4096, blk, 0, stream>>>(attn0b, offb, dwt1, attn1b);

    // Stage 3
    pw_mfma<<<2048, blk, 0, stream>>>(attn1b, wpP, conv1_b, x, out);
}

// Round 6
// 352.843 us; speedup vs baseline: 73.7712x; 1.1125x over previous
//
#include <hip/hip_runtime.h>

#define Bb 8
#define C  64
#define Hh 128
#define Ww 128
#define HW (Hh * Ww)

typedef __attribute__((ext_vector_type(8))) short b16x8;   // raw 16B block
typedef __attribute__((ext_vector_type(4))) float f32x4;
typedef _Float16 f16x8 __attribute__((ext_vector_type(8)));
typedef _Float16 h2 __attribute__((ext_vector_type(2)));
typedef __fp16 fp16x2cv __attribute__((ext_vector_type(2)));  // cvt_pkrtz ret

__device__ __forceinline__ ushort f2h(float f) {
    union { _Float16 h; ushort u; } z; z.h = (_Float16)f; return z.u;
}
__device__ __forceinline__ h2 u2h(uint u) {
    union { uint u; h2 h; } x; x.u = u; return x.h;
}
__device__ __forceinline__ uint h2u(h2 h) {
    union { uint u; h2 h; } x; x.h = h; return x.u;
}
__device__ __forceinline__ uint pkrtz_u(float a, float b) {
    union { fp16x2cv h; uint u; } z;
    z.h = __builtin_amdgcn_cvt_pkrtz(a, b); return z.u;
}
__device__ __forceinline__ f16x8 s2h8(b16x8 s) {
    union { b16x8 s; f16x8 h; } x; x.s = s; return x.h;
}

// ---------------------------------------------------------------------------
// NCHW fp32 -> NHWC fp16 (c innermost), transposed through LDS.
// ---------------------------------------------------------------------------
__global__ void pack_nhwc(const float* __restrict__ in, ushort* __restrict__ out) {
    __shared__ ushort t[64][65];
    const int bx = blockIdx.x;
    const int b = bx >> 8, rem = bx & 255, h = rem >> 1, w0 = (rem & 1) << 6;
    const int x = threadIdx.x, wl = x & 63, cs = x >> 6;
    const float* ip = in + (((size_t)b * 64) << 14) + (h << 7) + w0 + wl;
    #pragma unroll
    for (int i = 0; i < 16; ++i) {
        const int c = i * 4 + cs;
        t[wl][c] = f2h(ip[(size_t)c << 14]);
    }
    __syncthreads();
    ushort* op = out + ((size_t)((b * Hh + h) * Ww + w0)) * 64 + wl;
    #pragma unroll
    for (int i = 0; i < 16; ++i) {
        const int w = i * 4 + cs;
        op[(size_t)w * 64] = t[w][wl];
    }
}

// Weight pack: OIHW fp32 -> [S][OCP][32] fp16 (slice s: tap s>>1, c-half s&1).
__global__ void pack_w(const float* __restrict__ src, ushort* __restrict__ dst,
                       int OC, int OCP, int KK, int n) {
    const int idx = blockIdx.x * 256 + threadIdx.x;
    if (idx >= n) return;
    const int kk = idx & 31;
    const int oc = (idx >> 5) % OCP;
    const int s = idx / (32 * OCP);
    const int c = (s & 1) * 32 + kk;
    const int t = s >> 1;
    const float v = (oc < OC) ? src[((size_t)oc * 64 + c) * KK + t] : 0.f;
    dst[idx] = f2h(v);
}

// Depthwise weight transpose: [C][KK] -> [KK][C] fp16.
__global__ void pack_dwt(const float* __restrict__ src, ushort* __restrict__ dst, int KK) {
    const int i = blockIdx.x * 256 + threadIdx.x;
    if (i < KK * 64) {
        const int t = i >> 6, ch = i & 63;
        dst[i] = f2h(src[ch * KK + t]);
    }
}

// ---------------------------------------------------------------------------
// Offset conv as MFMA implicit GEMM (fp16) -> pixel-interleaved [B*HW][S] fp16.
// ---------------------------------------------------------------------------
template<int K, int PAD, int DIL, int OCP, int KR>
__global__ __launch_bounds__(256, 2) void conv_mfma(
    const ushort* __restrict__ xp,
    const ushort* __restrict__ wp,
    const float* __restrict__ bias,
    ushort* __restrict__ outp) {
    constexpr int WIDTH = 64 + (K - 1) * DIL;
    constexpr int S = 2 * K * K;
    constexpr int NT = OCP / 16;
    constexpr int TPW = (NT + 3) / 4;
    __shared__ __align__(16) ushort lds[KR * WIDTH * 64];

    const int bx = blockIdx.x;
    const int b = bx >> 8, rem = bx & 255, h = rem >> 1, w0 = (rem & 1) << 6;
    const int tid = threadIdx.x, lane = tid & 63, wid = tid >> 6;
    const int l15 = lane & 15, lg = lane >> 4;

    f32x4 acc[TPW][4] = {};

    const int nph = (K + KR - 1) / KR;
    for (int ph = 0; ph < nph; ++ph) {
        const int kr0 = ph * KR;
        const int krn = (K - kr0 < KR) ? (K - kr0) : KR;
        __syncthreads();
        const int chunks = krn * WIDTH * 8;
        for (int q = tid; q < chunks; q += 256) {
            const int ki = q / (WIDTH * 8);
            const int r2 = q - ki * (WIDTH * 8);
            const int widx = r2 >> 3, csl = r2 & 7;
            const int y = h - PAD + (kr0 + ki) * DIL;
            const int w = w0 - PAD + widx;
            uint4 v = make_uint4(0, 0, 0, 0);
            if ((unsigned)y < (unsigned)Hh && (unsigned)w < (unsigned)Ww)
                v = *(const uint4*)(xp + (((size_t)(b * Hh + y) * Ww + w) << 6) + (csl << 3));
            ((uint4*)lds)[(ki * WIDTH + widx) * 8 + (csl ^ (widx & 7))] = v;
        }
        __syncthreads();

        const int t0 = kr0 * K, t1 = (kr0 + krn) * K;
        for (int t = t0; t < t1; ++t) {
            const int ki = t / K - kr0;
            const int kj = t - (t / K) * K;
            const int s0 = 2 * t;
            b16x8 a[2][TPW];
            #pragma unroll
            for (int i = 0; i < TPW; ++i) {
                if (wid + 4 * i < NT) {
                    const int ot = wid + 4 * i;
                    const size_t abase = ((size_t)(ot * 16 + l15)) * 32 + lg * 8;
                    a[0][i] = *(const b16x8*)(wp + (size_t)s0 * (OCP * 32) + abase);
                    a[1][i] = *(const b16x8*)(wp + (size_t)(s0 + 1) * (OCP * 32) + abase);
                }
            }
            const int wbase = l15 + kj * DIL;
            int idx = (ki * WIDTH + wbase) * 8 + (lg ^ (wbase & 7));
            #pragma unroll
            for (int pt = 0; pt < 4; ++pt) {
                const b16x8 b0 = ((const b16x8*)lds)[idx];
                const b16x8 b1 = ((const b16x8*)lds)[idx ^ 4];
                #pragma unroll
                for (int i = 0; i < TPW; ++i) {
                    if (wid + 4 * i < NT) {
                        acc[i][pt] = __builtin_amdgcn_mfma_f32_16x16x32_f16(s2h8(a[0][i]), s2h8(b0), acc[i][pt], 0, 0, 0);
                        acc[i][pt] = __builtin_amdgcn_mfma_f32_16x16x32_f16(s2h8(a[1][i]), s2h8(b1), acc[i][pt], 0, 0, 0);
                    }
                }
                idx += 128;
            }
        }
    }

    __syncthreads();
    ushort* lo_ = lds;
    #pragma unroll
    for (int i = 0; i < TPW; ++i) {
        const int ot = wid + 4 * i;
        if (ot >= NT) continue;
        #pragma unroll
        for (int r = 0; r < 4; ++r) {
            const int oc = ot * 16 + lg * 4 + r;
            if (oc < S) {
                const float bv = bias[oc];
                #pragma unroll
                for (int pt = 0; pt < 4; ++pt)
                    lo_[(pt * 16 + l15) * S + oc] = f2h(acc[i][pt][r] + bv);
            }
        }
    }
    __syncthreads();
    const int nU = 64 * S / 2;
    uint* og = (uint*)outp + (size_t)((b * Hh + h) * Ww + w0) * (S / 2);
    for (int q = tid; q < nU; q += 256) og[q] = ((const uint*)lo_)[q];
}

// ---------------------------------------------------------------------------
// Deformable depthwise conv, NHWC fp16 in/out, packed-fp16 math.
// Setup: 32 pix x KK taps -> LDS {packed corner idx, (w00,w01),(w10,w11) f16}.
// Main: thread = (pixel, 8-ch group); per tap: broadcast ds_reads, 4 coalesced
//   uint4 corner loads, v_pk_fma_f16 bilinear + fp16 depthwise accumulate.
// ---------------------------------------------------------------------------
template <int K, int PAD, int DIL>
__global__ __launch_bounds__(256) void deform4(
    const ushort* __restrict__ xp,   // [B*HW][64] fp16
    const ushort* __restrict__ off,  // [B*HW][2KK] fp16
    const ushort* __restrict__ dwt,  // [KK][64] fp16
    ushort* __restrict__ outb) {     // [B*HW][64] fp16
    constexpr int KK = K * K;
    __shared__ ushort dwl[KK * 64];
    __shared__ uint sIdx[32 * KK];
    __shared__ __align__(8) uint2 sW[32 * KK];
    const int tid = threadIdx.x;
    const int pix0 = blockIdx.x * 32;

    for (int i = tid; i < KK * 32; i += 256)
        ((uint*)dwl)[i] = ((const uint*)dwt)[i];

    // --- setup phase ---
    const uint* og = (const uint*)off + (size_t)pix0 * KK;
    for (int q = tid; q < 32 * KK; q += 256) {
        const int pl2 = q / KK, t2 = q - pl2 * KK;
        const int pix = pix0 + pl2;
        const int h = (pix >> 7) & 127, w = pix & 127;
        const h2 oh = u2h(og[q]);
        const int ki = t2 / K, kj = t2 - ki * K;
        const float py = (float)(h - PAD + ki * DIL) + (float)oh.x;
        const float px = (float)(w - PAD + kj * DIL) + (float)oh.y;
        const float y0f = floorf(py), x0f = floorf(px);
        const float wy = py - y0f, wx = px - x0f;
        const int y0 = (int)y0f, x0 = (int)x0f;
        const int y1 = y0 + 1, x1 = x0 + 1;
        const float m00 = ((unsigned)y0 < 128u && (unsigned)x0 < 128u) ? 1.f : 0.f;
        const float m01 = ((unsigned)y0 < 128u && (unsigned)x1 < 128u) ? 1.f : 0.f;
        const float m10 = ((unsigned)y1 < 128u && (unsigned)x0 < 128u) ? 1.f : 0.f;
        const float m11 = ((unsigned)y1 < 128u && (unsigned)x1 < 128u) ? 1.f : 0.f;
        const int y0c = min(max(y0, 0), 127), y1c = min(max(y1, 0), 127);
        const int x0c = min(max(x0, 0), 127), x1c = min(max(x1, 0), 127);
        const float w00 = (1.f - wy) * (1.f - wx) * m00;
        const float w01 = (1.f - wy) * wx * m01;
        const float w10 = wy * (1.f - wx) * m10;
        const float w11 = wy * wx * m11;
        const int i00 = (y0c << 7) | x0c;
        const int i11 = (y1c << 7) | x1c;
        sIdx[q] = (uint)i00 | ((uint)i11 << 14);
        sW[q] = make_uint2(pkrtz_u(w00, w01), pkrtz_u(w10, w11));
    }
    __syncthreads();

    // --- main phase ---
    const int pl = tid >> 3, g = tid & 7;
    const int pix = pix0 + pl;
    const int b = pix0 >> 14;          // block-uniform -> scalar base
    const int gb = g << 3;
    const ushort* xb = xp + ((size_t)b << 20);

    h2 acc_h[4] = {};

    for (int t = 0; t < KK; ++t) {
        const int sid = pl * KK + t;
        const uint id = sIdx[sid];
        const uint2 w4 = sW[sid];
        const h2 wA = u2h(w4.x), wB = u2h(w4.y);
        const h2 w00b = {wA.x, wA.x}, w01b = {wA.y, wA.y};
        const h2 w10b = {wB.x, wB.x}, w11b = {wB.y, wB.y};
        const int i00 = id & 16383;
        const int i11 = (id >> 14) & 16383;
        const int i01 = (i00 & ~127) | (i11 & 127);
        const int i10 = (i11 & ~127) | (i00 & 127);
        const uint4 qa = *(const uint4*)(xb + (i00 << 6) + gb);
        const uint4 qb = *(const uint4*)(xb + (i01 << 6) + gb);
        const uint4 qc = *(const uint4*)(xb + (i10 << 6) + gb);
        const uint4 qd = *(const uint4*)(xb + (i11 << 6) + gb);
        const uint4 dwv = *(const uint4*)(dwl + (t << 6) + gb);
        const uint* A = (const uint*)&qa;
        const uint* Bv = (const uint*)&qb;
        const uint* Cv = (const uint*)&qc;
        const uint* D = (const uint*)&qd;
        const uint* Dw = (const uint*)&dwv;
        #pragma unroll
        for (int j = 0; j < 4; ++j) {
            h2 v = u2h(A[j]) * w00b;
            v += u2h(Bv[j]) * w01b;
            v += u2h(Cv[j]) * w10b;
            v += u2h(D[j]) * w11b;
            acc_h[j] += v * u2h(Dw[j]);
        }
    }

    uint o4[4];
    #pragma unroll
    for (int j = 0; j < 4; ++j) o4[j] = h2u(acc_h[j]);
    *(uint4*)(outb + ((size_t)pix << 6) + gb) = *(uint4*)o4;
}

// ---------------------------------------------------------------------------
// Fused 1x1 conv (fp16 MFMA) + bias + u*attn. attn NHWC fp16; x/out NCHW f32.
// ---------------------------------------------------------------------------
__global__ __launch_bounds__(256) void pw_mfma(
    const ushort* __restrict__ attn, const ushort* __restrict__ wp2,
    const float* __restrict__ b1, const float* __restrict__ x,
    float* __restrict__ out) {
    __shared__ __align__(16) ushort lds[64 * 64];
    const int tid = threadIdx.x, lane = tid & 63, wid = tid >> 6;
    const int l15 = lane & 15, lg = lane >> 4;
    const int pix0 = blockIdx.x << 6;

    const uint4* src = (const uint4*)(attn + ((size_t)pix0 << 6));
    for (int q = tid; q < 512; q += 256) {
        const int widx = q >> 3, csl = q & 7;
        ((uint4*)lds)[widx * 8 + (csl ^ (widx & 7))] = src[q];
    }
    __syncthreads();

    const b16x8 a0 = *(const b16x8*)(wp2 + ((size_t)(wid * 16 + l15)) * 32 + lg * 8);
    const b16x8 a1 = *(const b16x8*)(wp2 + ((size_t)(64 + wid * 16 + l15)) * 32 + lg * 8);
    f32x4 acc[4] = {};
    #pragma unroll
    for (int pt = 0; pt < 4; ++pt) {
        const int wb = pt * 16 + l15;
        const int idx = wb * 8 + (lg ^ (wb & 7));
        const b16x8 b0 = ((const b16x8*)lds)[idx];
        const b16x8 b1v = ((const b16x8*)lds)[idx ^ 4];
        acc[pt] = __builtin_amdgcn_mfma_f32_16x16x32_f16(s2h8(a0), s2h8(b0), acc[pt], 0, 0, 0);
        acc[pt] = __builtin_amdgcn_mfma_f32_16x16x32_f16(s2h8(a1), s2h8(b1v), acc[pt], 0, 0, 0);
    }

    const int b = pix0 >> 14, hw0 = pix0 & 16383;
    #pragma unroll
    for (int r = 0; r < 4; ++r) {
        const int oc = wid * 16 + lg * 4 + r;
        const float bv = b1[oc];
        const size_t base = (((size_t)b * 64 + oc) << 14) + hw0;
        #pragma unroll
        for (int pt = 0; pt < 4; ++pt) {
            const size_t oi = base + pt * 16 + l15;
            out[oi] = x[oi] * (acc[pt][r] + bv);
        }
    }
}

extern "C" void kernel_launch(void* const* d_in, const int* in_sizes, int n_in,
                              void* d_out, int out_size, void* d_ws, size_t ws_size,
                              hipStream_t stream) {
    const float* x       = (const float*)d_in[0];
    const float* off0_w  = (const float*)d_in[1];
    const float* off0_b  = (const float*)d_in[2];
    const float* dw0_w   = (const float*)d_in[3];
    const float* off1_w  = (const float*)d_in[4];
    const float* off1_b  = (const float*)d_in[5];
    const float* dw1_w   = (const float*)d_in[6];
    const float* conv1_w = (const float*)d_in[7];
    const float* conv1_b = (const float*)d_in[8];
    float* out = (float*)d_out;

    const size_t NPX = (size_t)Bb * HW;
    ushort* xp     = (ushort*)d_ws;
    ushort* attn0b = xp + NPX * 64;
    ushort* attn1b = attn0b + NPX * 64;
    ushort* offb   = attn1b + NPX * 64;
    ushort* wp0    = offb + NPX * 98;
    ushort* wp1    = wp0 + 50 * 64 * 32;
    ushort* wpP    = wp1 + 98 * 112 * 32;
    ushort* dwt0   = wpP + 2 * 64 * 32;
    ushort* dwt1   = dwt0 + 25 * 64;

    const dim3 blk(256);

    pack_nhwc<<<2048, blk, 0, stream>>>(x, xp);
    pack_w<<<(50 * 64 * 32 + 255) / 256, blk, 0, stream>>>(off0_w, wp0, 50, 64, 25, 50 * 64 * 32);
    pack_w<<<(98 * 112 * 32 + 255) / 256, blk, 0, stream>>>(off1_w, wp1, 98, 112, 49, 98 * 112 * 32);
    pack_w<<<16, blk, 0, stream>>>(conv1_w, wpP, 64, 64, 1, 2 * 64 * 32);
    pack_dwt<<<(25 * 64 + 255) / 256, blk, 0, stream>>>(dw0_w, dwt0, 25);
    pack_dwt<<<(49 * 64 + 255) / 256, blk, 0, stream>>>(dw1_w, dwt1, 49);

    // Stage 1
    conv_mfma<5, 2, 1, 64, 5><<<2048, blk, 0, stream>>>(xp, wp0, off0_b, offb);
    deform4<5, 2, 1><<<4096, blk, 0, stream>>>(xp, offb, dwt0, attn0b);

    // Stage 2
    conv_mfma<7, 9, 3, 112, 4><<<2048, blk, 0, stream>>>(attn0b, wp1, off1_b, offb);
    deform4<7, 9, 3><<<4096, blk, 0, stream>>>(attn0b, offb, dwt1, attn1b);

    // Stage 3
    pw_mfma<<<2048, blk, 0, stream>>>(attn1b, wpP, conv1_b, x, out);
}

// Round 7
// 312.145 us; speedup vs baseline: 83.3896x; 1.1304x over previous
//
#include <hip/hip_runtime.h>

#define Bb 8
#define C  64
#define Hh 128
#define Ww 128
#define HW (Hh * Ww)

typedef __attribute__((ext_vector_type(8))) short b16x8;   // raw 16B block
typedef __attribute__((ext_vector_type(4))) float f32x4;
typedef _Float16 f16x8 __attribute__((ext_vector_type(8)));
typedef _Float16 h2 __attribute__((ext_vector_type(2)));
typedef __fp16 fp16x2cv __attribute__((ext_vector_type(2)));  // cvt_pkrtz ret

__device__ __forceinline__ ushort f2h(float f) {
    union { _Float16 h; ushort u; } z; z.h = (_Float16)f; return z.u;
}
__device__ __forceinline__ h2 u2h(uint u) {
    union { uint u; h2 h; } x; x.u = u; return x.h;
}
__device__ __forceinline__ uint h2u(h2 h) {
    union { uint u; h2 h; } x; x.h = h; return x.u;
}
__device__ __forceinline__ uint pkrtz_u(float a, float b) {
    union { fp16x2cv h; uint u; } z;
    z.h = __builtin_amdgcn_cvt_pkrtz(a, b); return z.u;
}
__device__ __forceinline__ f16x8 s2h8(b16x8 s) {
    union { b16x8 s; f16x8 h; } x; x.s = s; return x.h;
}

// ---------------------------------------------------------------------------
// NCHW fp32 -> NHWC fp16 (c innermost), transposed through LDS.
// ---------------------------------------------------------------------------
__global__ void pack_nhwc(const float* __restrict__ in, ushort* __restrict__ out) {
    __shared__ ushort t[64][65];
    const int bx = blockIdx.x;
    const int b = bx >> 8, rem = bx & 255, h = rem >> 1, w0 = (rem & 1) << 6;
    const int x = threadIdx.x, wl = x & 63, cs = x >> 6;
    const float* ip = in + (((size_t)b * 64) << 14) + (h << 7) + w0 + wl;
    #pragma unroll
    for (int i = 0; i < 16; ++i) {
        const int c = i * 4 + cs;
        t[wl][c] = f2h(ip[(size_t)c << 14]);
    }
    __syncthreads();
    ushort* op = out + ((size_t)((b * Hh + h) * Ww + w0)) * 64 + wl;
    #pragma unroll
    for (int i = 0; i < 16; ++i) {
        const int w = i * 4 + cs;
        op[(size_t)w * 64] = t[w][wl];
    }
}

// Weight pack: OIHW fp32 -> [S][OCP][32] fp16 (slice s: tap s>>1, c-half s&1).
__global__ void pack_w(const float* __restrict__ src, ushort* __restrict__ dst,
                       int OC, int OCP, int KK, int n) {
    const int idx = blockIdx.x * 256 + threadIdx.x;
    if (idx >= n) return;
    const int kk = idx & 31;
    const int oc = (idx >> 5) % OCP;
    const int s = idx / (32 * OCP);
    const int c = (s & 1) * 32 + kk;
    const int t = s >> 1;
    const float v = (oc < OC) ? src[((size_t)oc * 64 + c) * KK + t] : 0.f;
    dst[idx] = f2h(v);
}

// Depthwise weight transpose: [C][KK] -> [KK][C] fp16.
__global__ void pack_dwt(const float* __restrict__ src, ushort* __restrict__ dst, int KK) {
    const int i = blockIdx.x * 256 + threadIdx.x;
    if (i < KK * 64) {
        const int t = i >> 6, ch = i & 63;
        dst[i] = f2h(src[ch * KK + t]);
    }
}

// ---------------------------------------------------------------------------
// Offset conv as MFMA implicit GEMM (fp16), full-row tile (128 pixels/block).
// Grid = B*H = 1024. Weights re-read once per row (not per 64-px segment).
// KR k-rows staged per phase; epilogue transposes to [pix][S] with padded
// stride SP=S+2 to avoid LDS bank conflicts, then flat coalesced store.
// ---------------------------------------------------------------------------
template<int K, int PAD, int DIL, int OCP, int KR>
__global__ __launch_bounds__(256, 4) void conv_mfma(
    const ushort* __restrict__ xp,
    const ushort* __restrict__ wp,
    const float* __restrict__ bias,
    ushort* __restrict__ outp) {
    constexpr int WIDTH = 128 + (K - 1) * DIL;
    constexpr int S = 2 * K * K;
    constexpr int SP = S + 2;
    constexpr int NT = OCP / 16;
    constexpr int TPW = (NT + 3) / 4;
    constexpr int STG = KR * WIDTH * 64;
    constexpr int EPI = 128 * SP;
    constexpr int LN = STG > EPI ? STG : EPI;
    __shared__ __align__(16) ushort lds[LN];

    const int bx = blockIdx.x;
    const int b = bx >> 7, h = bx & 127;
    const int tid = threadIdx.x, lane = tid & 63, wid = tid >> 6;
    const int l15 = lane & 15, lg = lane >> 4;

    f32x4 acc[TPW][8] = {};

    const int nph = (K + KR - 1) / KR;
    for (int ph = 0; ph < nph; ++ph) {
        const int kr0 = ph * KR;
        const int krn = (K - kr0 < KR) ? (K - kr0) : KR;
        __syncthreads();
        const int chunks = krn * WIDTH * 8;
        for (int q = tid; q < chunks; q += 256) {
            const int ki = q / (WIDTH * 8);
            const int r2 = q - ki * (WIDTH * 8);
            const int widx = r2 >> 3, csl = r2 & 7;
            const int y = h - PAD + (kr0 + ki) * DIL;
            const int w = -PAD + widx;
            uint4 v = make_uint4(0, 0, 0, 0);
            if ((unsigned)y < 128u && (unsigned)w < 128u)
                v = *(const uint4*)(xp + (((size_t)(b * 128 + y) * 128 + w) << 6) + (csl << 3));
            ((uint4*)lds)[(ki * WIDTH + widx) * 8 + (csl ^ (widx & 7))] = v;
        }
        __syncthreads();

        const int t1 = (kr0 + krn) * K;
        for (int t = kr0 * K; t < t1; ++t) {
            const int ki = t / K - kr0;
            const int kj = t - (t / K) * K;
            const int s0 = 2 * t;
            b16x8 a[2][TPW];
            #pragma unroll
            for (int i = 0; i < TPW; ++i) {
                if (wid + 4 * i < NT) {
                    const int ot = wid + 4 * i;
                    const size_t ab = ((size_t)(ot * 16 + l15)) * 32 + lg * 8;
                    a[0][i] = *(const b16x8*)(wp + (size_t)s0 * (OCP * 32) + ab);
                    a[1][i] = *(const b16x8*)(wp + (size_t)(s0 + 1) * (OCP * 32) + ab);
                }
            }
            const int wb0 = l15 + kj * DIL;
            int idx = (ki * WIDTH + wb0) * 8 + (lg ^ (wb0 & 7));
            #pragma unroll
            for (int pt = 0; pt < 8; ++pt) {
                const b16x8 b0 = ((const b16x8*)lds)[idx];
                const b16x8 b1 = ((const b16x8*)lds)[idx ^ 4];
                #pragma unroll
                for (int i = 0; i < TPW; ++i) {
                    if (wid + 4 * i < NT) {
                        acc[i][pt] = __builtin_amdgcn_mfma_f32_16x16x32_f16(s2h8(a[0][i]), s2h8(b0), acc[i][pt], 0, 0, 0);
                        acc[i][pt] = __builtin_amdgcn_mfma_f32_16x16x32_f16(s2h8(a[1][i]), s2h8(b1), acc[i][pt], 0, 0, 0);
                    }
                }
                idx += 128;
            }
        }
    }

    // Epilogue: acc -> LDS [128 pix][SP], then flat coalesced copy (S cols).
    __syncthreads();
    #pragma unroll
    for (int i = 0; i < TPW; ++i) {
        const int ot = wid + 4 * i;
        if (ot >= NT) continue;
        #pragma unroll
        for (int r = 0; r < 4; ++r) {
            const int oc = ot * 16 + lg * 4 + r;
            if (oc < S) {
                const float bv = bias[oc];
                #pragma unroll
                for (int pt = 0; pt < 8; ++pt)
                    lds[(pt * 16 + l15) * SP + oc] = f2h(acc[i][pt][r] + bv);
            }
        }
    }
    __syncthreads();
    constexpr int SH = S / 2, SPH = SP / 2;
    const uint* lu = (const uint*)lds;
    uint* og = (uint*)outp + ((size_t)bx << 7) * SH;
    for (int q = tid; q < 128 * SH; q += 256) {
        const int pix = q / SH, s = q - pix * SH;
        og[q] = lu[pix * SPH + s];
    }
}

// ---------------------------------------------------------------------------
// Deformable depthwise conv, NHWC fp16 in/out, packed-fp16 math.
// ---------------------------------------------------------------------------
template <int K, int PAD, int DIL>
__global__ __launch_bounds__(256) void deform4(
    const ushort* __restrict__ xp,   // [B*HW][64] fp16
    const ushort* __restrict__ off,  // [B*HW][2KK] fp16
    const ushort* __restrict__ dwt,  // [KK][64] fp16
    ushort* __restrict__ outb) {     // [B*HW][64] fp16
    constexpr int KK = K * K;
    __shared__ ushort dwl[KK * 64];
    __shared__ uint sIdx[32 * KK];
    __shared__ __align__(8) uint2 sW[32 * KK];
    const int tid = threadIdx.x;
    const int pix0 = blockIdx.x * 32;

    for (int i = tid; i < KK * 32; i += 256)
        ((uint*)dwl)[i] = ((const uint*)dwt)[i];

    // --- setup phase ---
    const uint* og = (const uint*)off + (size_t)pix0 * KK;
    for (int q = tid; q < 32 * KK; q += 256) {
        const int pl2 = q / KK, t2 = q - pl2 * KK;
        const int pix = pix0 + pl2;
        const int h = (pix >> 7) & 127, w = pix & 127;
        const h2 oh = u2h(og[q]);
        const int ki = t2 / K, kj = t2 - ki * K;
        const float py = (float)(h - PAD + ki * DIL) + (float)oh.x;
        const float px = (float)(w - PAD + kj * DIL) + (float)oh.y;
        const float y0f = floorf(py), x0f = floorf(px);
        const float wy = py - y0f, wx = px - x0f;
        const int y0 = (int)y0f, x0 = (int)x0f;
        const int y1 = y0 + 1, x1 = x0 + 1;
        const float m00 = ((unsigned)y0 < 128u && (unsigned)x0 < 128u) ? 1.f : 0.f;
        const float m01 = ((unsigned)y0 < 128u && (unsigned)x1 < 128u) ? 1.f : 0.f;
        const float m10 = ((unsigned)y1 < 128u && (unsigned)x0 < 128u) ? 1.f : 0.f;
        const float m11 = ((unsigned)y1 < 128u && (unsigned)x1 < 128u) ? 1.f : 0.f;
        const int y0c = min(max(y0, 0), 127), y1c = min(max(y1, 0), 127);
        const int x0c = min(max(x0, 0), 127), x1c = min(max(x1, 0), 127);
        const float w00 = (1.f - wy) * (1.f - wx) * m00;
        const float w01 = (1.f - wy) * wx * m01;
        const float w10 = wy * (1.f - wx) * m10;
        const float w11 = wy * wx * m11;
        const int i00 = (y0c << 7) | x0c;
        const int i11 = (y1c << 7) | x1c;
        sIdx[q] = (uint)i00 | ((uint)i11 << 14);
        sW[q] = make_uint2(pkrtz_u(w00, w01), pkrtz_u(w10, w11));
    }
    __syncthreads();

    // --- main phase ---
    const int pl = tid >> 3, g = tid & 7;
    const int pix = pix0 + pl;
    const int b = pix0 >> 14;          // block-uniform -> scalar base
    const int gb = g << 3;
    const ushort* xb = xp + ((size_t)b << 20);

    h2 acc_h[4] = {};

    for (int t = 0; t < KK; ++t) {
        const int sid = pl * KK + t;
        const uint id = sIdx[sid];
        const uint2 w4 = sW[sid];
        const h2 wA = u2h(w4.x), wB = u2h(w4.y);
        const h2 w00b = {wA.x, wA.x}, w01b = {wA.y, wA.y};
        const h2 w10b = {wB.x, wB.x}, w11b = {wB.y, wB.y};
        const int i00 = id & 16383;
        const int i11 = (id >> 14) & 16383;
        const int i01 = (i00 & ~127) | (i11 & 127);
        const int i10 = (i11 & ~127) | (i00 & 127);
        const uint4 qa = *(const uint4*)(xb + (i00 << 6) + gb);
        const uint4 qb = *(const uint4*)(xb + (i01 << 6) + gb);
        const uint4 qc = *(const uint4*)(xb + (i10 << 6) + gb);
        const uint4 qd = *(const uint4*)(xb + (i11 << 6) + gb);
        const uint4 dwv = *(const uint4*)(dwl + (t << 6) + gb);
        const uint* A = (const uint*)&qa;
        const uint* Bv = (const uint*)&qb;
        const uint* Cv = (const uint*)&qc;
        const uint* D = (const uint*)&qd;
        const uint* Dw = (const uint*)&dwv;
        #pragma unroll
        for (int j = 0; j < 4; ++j) {
            h2 v = u2h(A[j]) * w00b;
            v += u2h(Bv[j]) * w01b;
            v += u2h(Cv[j]) * w10b;
            v += u2h(D[j]) * w11b;
            acc_h[j] += v * u2h(Dw[j]);
        }
    }

    uint o4[4];
    #pragma unroll
    for (int j = 0; j < 4; ++j) o4[j] = h2u(acc_h[j]);
    *(uint4*)(outb + ((size_t)pix << 6) + gb) = *(uint4*)o4;
}

// ---------------------------------------------------------------------------
// Fused 1x1 conv (fp16 MFMA) + bias + u*attn. attn NHWC fp16; x/out NCHW f32.
// ---------------------------------------------------------------------------
__global__ __launch_bounds__(256) void pw_mfma(
    const ushort* __restrict__ attn, const ushort* __restrict__ wp2,
    const float* __restrict__ b1, const float* __restrict__ x,
    float* __restrict__ out) {
    __shared__ __align__(16) ushort lds[64 * 64];
    const int tid = threadIdx.x, lane = tid & 63, wid = tid >> 6;
    const int l15 = lane & 15, lg = lane >> 4;
    const int pix0 = blockIdx.x << 6;

    const uint4* src = (const uint4*)(attn + ((size_t)pix0 << 6));
    for (int q = tid; q < 512; q += 256) {
        const int widx = q >> 3, csl = q & 7;
        ((uint4*)lds)[widx * 8 + (csl ^ (widx & 7))] = src[q];
    }
    __syncthreads();

    const b16x8 a0 = *(const b16x8*)(wp2 + ((size_t)(wid * 16 + l15)) * 32 + lg * 8);
    const b16x8 a1 = *(const b16x8*)(wp2 + ((size_t)(64 + wid * 16 + l15)) * 32 + lg * 8);
    f32x4 acc[4] = {};
    #pragma unroll
    for (int pt = 0; pt < 4; ++pt) {
        const int wb = pt * 16 + l15;
        const int idx = wb * 8 + (lg ^ (wb & 7));
        const b16x8 b0 = ((const b16x8*)lds)[idx];
        const b16x8 b1v = ((const b16x8*)lds)[idx ^ 4];
        acc[pt] = __builtin_amdgcn_mfma_f32_16x16x32_f16(s2h8(a0), s2h8(b0), acc[pt], 0, 0, 0);
        acc[pt] = __builtin_amdgcn_mfma_f32_16x16x32_f16(s2h8(a1), s2h8(b1v), acc[pt], 0, 0, 0);
    }

    const int b = pix0 >> 14, hw0 = pix0 & 16383;
    #pragma unroll
    for (int r = 0; r < 4; ++r) {
        const int oc = wid * 16 + lg * 4 + r;
        const float bv = b1[oc];
        const size_t base = (((size_t)b * 64 + oc) << 14) + hw0;
        #pragma unroll
        for (int pt = 0; pt < 4; ++pt) {
            const size_t oi = base + pt * 16 + l15;
            out[oi] = x[oi] * (acc[pt][r] + bv);
        }
    }
}

extern "C" void kernel_launch(void* const* d_in, const int* in_sizes, int n_in,
                              void* d_out, int out_size, void* d_ws, size_t ws_size,
                              hipStream_t stream) {
    const float* x       = (const float*)d_in[0];
    const float* off0_w  = (const float*)d_in[1];
    const float* off0_b  = (const float*)d_in[2];
    const float* dw0_w   = (const float*)d_in[3];
    const float* off1_w  = (const float*)d_in[4];
    const float* off1_b  = (const float*)d_in[5];
    const float* dw1_w   = (const float*)d_in[6];
    const float* conv1_w = (const float*)d_in[7];
    const float* conv1_b = (const float*)d_in[8];
    float* out = (float*)d_out;

    const size_t NPX = (size_t)Bb * HW;
    ushort* xp     = (ushort*)d_ws;
    ushort* attn0b = xp + NPX * 64;
    ushort* attn1b = attn0b + NPX * 64;
    ushort* offb   = attn1b + NPX * 64;
    ushort* wp0    = offb + NPX * 98;
    ushort* wp1    = wp0 + 50 * 64 * 32;
    ushort* wpP    = wp1 + 98 * 112 * 32;
    ushort* dwt0   = wpP + 2 * 64 * 32;
    ushort* dwt1   = dwt0 + 25 * 64;

    const dim3 blk(256);

    pack_nhwc<<<2048, blk, 0, stream>>>(x, xp);
    pack_w<<<(50 * 64 * 32 + 255) / 256, blk, 0, stream>>>(off0_w, wp0, 50, 64, 25, 50 * 64 * 32);
    pack_w<<<(98 * 112 * 32 + 255) / 256, blk, 0, stream>>>(off1_w, wp1, 98, 112, 49, 98 * 112 * 32);
    pack_w<<<16, blk, 0, stream>>>(conv1_w, wpP, 64, 64, 1, 2 * 64 * 32);
    pack_dwt<<<(25 * 64 + 255) / 256, blk, 0, stream>>>(dw0_w, dwt0, 25);
    pack_dwt<<<(49 * 64 + 255) / 256, blk, 0, stream>>>(dw1_w, dwt1, 49);

    // Stage 1
    conv_mfma<5, 2, 1, 64, 2><<<1024, blk, 0, stream>>>(xp, wp0, off0_b, offb);
    deform4<5, 2, 1><<<4096, blk, 0, stream>>>(xp, offb, dwt0, attn0b);

    // Stage 2
    conv_mfma<7, 9, 3, 112, 2><<<1024, blk, 0, stream>>>(attn0b, wp1, off1_b, offb);
    deform4<7, 9, 3><<<4096, blk, 0, stream>>>(attn0b, offb, dwt1, attn1b);

    // Stage 3
    pw_mfma<<<2048, blk, 0, stream>>>(attn1b, wpP, conv1_b, x, out);
}

// Round 8
// 308.829 us; speedup vs baseline: 84.2851x; 1.0107x over previous
//
#include <hip/hip_runtime.h>
#include <hip/hip_fp16.h>

#define Bb 8
#define C  64
#define Hh 128
#define Ww 128
#define HW (Hh * Ww)

typedef __attribute__((ext_vector_type(8))) short b16x8;   // raw 16B block
typedef __attribute__((ext_vector_type(4))) float f32x4;
typedef _Float16 f16x8 __attribute__((ext_vector_type(8)));
typedef __fp16 fp16x2cv __attribute__((ext_vector_type(2)));  // cvt_pkrtz ret

__device__ __forceinline__ ushort f2h(float f) {
    union { _Float16 h; ushort u; } z; z.h = (_Float16)f; return z.u;
}
__device__ __forceinline__ uint pkrtz_u(float a, float b) {
    union { fp16x2cv h; uint u; } z;
    z.h = __builtin_amdgcn_cvt_pkrtz(a, b); return z.u;
}
__device__ __forceinline__ f16x8 s2h8(b16x8 s) {
    union { b16x8 s; f16x8 h; } x; x.s = s; return x.h;
}
__device__ __forceinline__ __half2 u2hh(uint u) {
    union { uint u; __half2 h; } x; x.u = u; return x.h;
}
__device__ __forceinline__ uint hh2u(__half2 h) {
    union { uint u; __half2 h; } x; x.h = h; return x.u;
}
__device__ __forceinline__ float h2f_lo(uint u) {
    union { uint u; __half2 h; } x; x.u = u; return __low2float(x.h);
}
__device__ __forceinline__ float h2f_hi(uint u) {
    union { uint u; __half2 h; } x; x.u = u; return __high2float(x.h);
}

// ---------------------------------------------------------------------------
// NCHW fp32 -> NHWC fp16 (c innermost), transposed through LDS.
// ---------------------------------------------------------------------------
__global__ void pack_nhwc(const float* __restrict__ in, ushort* __restrict__ out) {
    __shared__ ushort t[64][65];
    const int bx = blockIdx.x;
    const int b = bx >> 8, rem = bx & 255, h = rem >> 1, w0 = (rem & 1) << 6;
    const int x = threadIdx.x, wl = x & 63, cs = x >> 6;
    const float* ip = in + (((size_t)b * 64) << 14) + (h << 7) + w0 + wl;
    #pragma unroll
    for (int i = 0; i < 16; ++i) {
        const int c = i * 4 + cs;
        t[wl][c] = f2h(ip[(size_t)c << 14]);
    }
    __syncthreads();
    ushort* op = out + ((size_t)((b * Hh + h) * Ww + w0)) * 64 + wl;
    #pragma unroll
    for (int i = 0; i < 16; ++i) {
        const int w = i * 4 + cs;
        op[(size_t)w * 64] = t[w][wl];
    }
}

// Weight pack: OIHW fp32 -> [S][OCP][32] fp16 (slice s: tap s>>1, c-half s&1).
__global__ void pack_w(const float* __restrict__ src, ushort* __restrict__ dst,
                       int OC, int OCP, int KK, int n) {
    const int idx = blockIdx.x * 256 + threadIdx.x;
    if (idx >= n) return;
    const int kk = idx & 31;
    const int oc = (idx >> 5) % OCP;
    const int s = idx / (32 * OCP);
    const int c = (s & 1) * 32 + kk;
    const int t = s >> 1;
    const float v = (oc < OC) ? src[((size_t)oc * 64 + c) * KK + t] : 0.f;
    dst[idx] = f2h(v);
}

// Depthwise weight transpose: [C][KK] -> [KK][C] fp16.
__global__ void pack_dwt(const float* __restrict__ src, ushort* __restrict__ dst, int KK) {
    const int i = blockIdx.x * 256 + threadIdx.x;
    if (i < KK * 64) {
        const int t = i >> 6, ch = i & 63;
        dst[i] = f2h(src[ch * KK + t]);
    }
}

// ---------------------------------------------------------------------------
// Offset conv as MFMA implicit GEMM (fp16), full-row tile (128 pixels/block).
// ---------------------------------------------------------------------------
template<int K, int PAD, int DIL, int OCP, int KR>
__global__ __launch_bounds__(256, 4) void conv_mfma(
    const ushort* __restrict__ xp,
    const ushort* __restrict__ wp,
    const float* __restrict__ bias,
    ushort* __restrict__ outp) {
    constexpr int WIDTH = 128 + (K - 1) * DIL;
    constexpr int S = 2 * K * K;
    constexpr int SP = S + 2;
    constexpr int NT = OCP / 16;
    constexpr int TPW = (NT + 3) / 4;
    constexpr int STG = KR * WIDTH * 64;
    constexpr int EPI = 128 * SP;
    constexpr int LN = STG > EPI ? STG : EPI;
    __shared__ __align__(16) ushort lds[LN];

    const int bx = blockIdx.x;
    const int b = bx >> 7, h = bx & 127;
    const int tid = threadIdx.x, lane = tid & 63, wid = tid >> 6;
    const int l15 = lane & 15, lg = lane >> 4;

    f32x4 acc[TPW][8] = {};

    const int nph = (K + KR - 1) / KR;
    for (int ph = 0; ph < nph; ++ph) {
        const int kr0 = ph * KR;
        const int krn = (K - kr0 < KR) ? (K - kr0) : KR;
        __syncthreads();
        const int chunks = krn * WIDTH * 8;
        for (int q = tid; q < chunks; q += 256) {
            const int ki = q / (WIDTH * 8);
            const int r2 = q - ki * (WIDTH * 8);
            const int widx = r2 >> 3, csl = r2 & 7;
            const int y = h - PAD + (kr0 + ki) * DIL;
            const int w = -PAD + widx;
            uint4 v = make_uint4(0, 0, 0, 0);
            if ((unsigned)y < 128u && (unsigned)w < 128u)
                v = *(const uint4*)(xp + (((size_t)(b * 128 + y) * 128 + w) << 6) + (csl << 3));
            ((uint4*)lds)[(ki * WIDTH + widx) * 8 + (csl ^ (widx & 7))] = v;
        }
        __syncthreads();

        const int t1 = (kr0 + krn) * K;
        for (int t = kr0 * K; t < t1; ++t) {
            const int ki = t / K - kr0;
            const int kj = t - (t / K) * K;
            const int s0 = 2 * t;
            b16x8 a[2][TPW];
            #pragma unroll
            for (int i = 0; i < TPW; ++i) {
                if (wid + 4 * i < NT) {
                    const int ot = wid + 4 * i;
                    const size_t ab = ((size_t)(ot * 16 + l15)) * 32 + lg * 8;
                    a[0][i] = *(const b16x8*)(wp + (size_t)s0 * (OCP * 32) + ab);
                    a[1][i] = *(const b16x8*)(wp + (size_t)(s0 + 1) * (OCP * 32) + ab);
                }
            }
            const int wb0 = l15 + kj * DIL;
            int idx = (ki * WIDTH + wb0) * 8 + (lg ^ (wb0 & 7));
            #pragma unroll
            for (int pt = 0; pt < 8; ++pt) {
                const b16x8 b0 = ((const b16x8*)lds)[idx];
                const b16x8 b1 = ((const b16x8*)lds)[idx ^ 4];
                #pragma unroll
                for (int i = 0; i < TPW; ++i) {
                    if (wid + 4 * i < NT) {
                        acc[i][pt] = __builtin_amdgcn_mfma_f32_16x16x32_f16(s2h8(a[0][i]), s2h8(b0), acc[i][pt], 0, 0, 0);
                        acc[i][pt] = __builtin_amdgcn_mfma_f32_16x16x32_f16(s2h8(a[1][i]), s2h8(b1), acc[i][pt], 0, 0, 0);
                    }
                }
                idx += 128;
            }
        }
    }

    // Epilogue: acc -> LDS [128 pix][SP], then flat coalesced copy (S cols).
    __syncthreads();
    #pragma unroll
    for (int i = 0; i < TPW; ++i) {
        const int ot = wid + 4 * i;
        if (ot >= NT) continue;
        #pragma unroll
        for (int r = 0; r < 4; ++r) {
            const int oc = ot * 16 + lg * 4 + r;
            if (oc < S) {
                const float bv = bias[oc];
                #pragma unroll
                for (int pt = 0; pt < 8; ++pt)
                    lds[(pt * 16 + l15) * SP + oc] = f2h(acc[i][pt][r] + bv);
            }
        }
    }
    __syncthreads();
    constexpr int SH = S / 2, SPH = SP / 2;
    const uint* lu = (const uint*)lds;
    uint* og = (uint*)outp + ((size_t)bx << 7) * SH;
    for (int q = tid; q < 128 * SH; q += 256) {
        const int pix = q / SH, s = q - pix * SH;
        og[q] = lu[pix * SPH + s];
    }
}

// ---------------------------------------------------------------------------
// Deformable depthwise conv, NHWC fp16, __half2 packed math, 2-deep tap
// pipeline (corner loads for tap t+1 in flight while tap t computes).
// Setup stores per-(pixel,tap): i00 | i11<<14 | dx<<28, and 4 f16 weights.
// ---------------------------------------------------------------------------
template <int K, int PAD, int DIL>
__global__ __launch_bounds__(256, 4) void deform5(
    const ushort* __restrict__ xp,   // [B*HW][64] fp16
    const ushort* __restrict__ off,  // [B*HW][2KK] fp16
    const ushort* __restrict__ dwt,  // [KK][64] fp16
    ushort* __restrict__ outb) {     // [B*HW][64] fp16
    constexpr int KK = K * K;
    __shared__ ushort dwl[KK * 64];
    __shared__ uint sIdx[32 * KK];
    __shared__ __align__(8) uint2 sW[32 * KK];
    const int tid = threadIdx.x;
    const int pix0 = blockIdx.x * 32;

    for (int i = tid; i < KK * 32; i += 256)
        ((uint*)dwl)[i] = ((const uint*)dwt)[i];

    // --- setup phase ---
    const uint* og = (const uint*)off + (size_t)pix0 * KK;
    for (int q = tid; q < 32 * KK; q += 256) {
        const int pl2 = q / KK, t2 = q - pl2 * KK;
        const int pix = pix0 + pl2;
        const int h = (pix >> 7) & 127, w = pix & 127;
        const uint od = og[q];
        const int ki = t2 / K, kj = t2 - ki * K;
        const float py = (float)(h - PAD + ki * DIL) + h2f_lo(od);
        const float px = (float)(w - PAD + kj * DIL) + h2f_hi(od);
        const float y0f = floorf(py), x0f = floorf(px);
        const float wy = py - y0f, wx = px - x0f;
        const int y0 = (int)y0f, x0 = (int)x0f;
        const int y1 = y0 + 1, x1 = x0 + 1;
        const float m00 = ((unsigned)y0 < 128u && (unsigned)x0 < 128u) ? 1.f : 0.f;
        const float m01 = ((unsigned)y0 < 128u && (unsigned)x1 < 128u) ? 1.f : 0.f;
        const float m10 = ((unsigned)y1 < 128u && (unsigned)x0 < 128u) ? 1.f : 0.f;
        const float m11 = ((unsigned)y1 < 128u && (unsigned)x1 < 128u) ? 1.f : 0.f;
        const int y0c = min(max(y0, 0), 127), y1c = min(max(y1, 0), 127);
        const int x0c = min(max(x0, 0), 127), x1c = min(max(x1, 0), 127);
        const float w00 = (1.f - wy) * (1.f - wx) * m00;
        const float w01 = (1.f - wy) * wx * m01;
        const float w10 = wy * (1.f - wx) * m10;
        const float w11 = wy * wx * m11;
        const int i00 = (y0c << 7) | x0c;
        const int i11 = (y1c << 7) | x1c;
        const int dx = x1c - x0c;                      // 0 or 1
        sIdx[q] = (uint)i00 | ((uint)i11 << 14) | ((uint)dx << 28);
        sW[q] = make_uint2(pkrtz_u(w00, w01), pkrtz_u(w10, w11));
    }
    __syncthreads();

    // --- main phase: thread = (pixel pl, 8-ch group g), 2-deep pipeline ---
    const int pl = tid >> 3, g = tid & 7;
    const int pix = pix0 + pl;
    const int bimg = pix0 >> 14;       // block-uniform
    const int gb = g << 3;
    const char* xb8 = (const char*)(xp + ((size_t)bimg << 20)) + (gb << 1);
    const int base = pl * KK;

    __half2 acc_h[4] = {};

#define CORNERS(ID, A_, B_, C_, D_)                                          \
    {                                                                        \
        const int i00_ = (ID) & 16383;                                       \
        const int i11_ = ((ID) >> 14) & 16383;                               \
        const int dxb_ = ((ID) >> 21) & 128;                                 \
        const int o00_ = i00_ << 7, o11_ = i11_ << 7;                        \
        A_ = *(const uint4*)(xb8 + o00_);                                    \
        B_ = *(const uint4*)(xb8 + (o00_ + dxb_));                           \
        C_ = *(const uint4*)(xb8 + (o11_ - dxb_));                           \
        D_ = *(const uint4*)(xb8 + o11_);                                    \
    }

#define MATH(T, A_, B_, C_, D_, W_)                                          \
    {                                                                        \
        const __half2 wv0 = u2hh((W_).x), wv1 = u2hh((W_).y);                \
        const __half2 w00b = __low2half2(wv0), w01b = __high2half2(wv0);     \
        const __half2 w10b = __low2half2(wv1), w11b = __high2half2(wv1);     \
        const uint4 dwv = *(const uint4*)(dwl + ((T) << 6) + gb);            \
        const uint* Ap = (const uint*)&(A_);                                 \
        const uint* Bp = (const uint*)&(B_);                                 \
        const uint* Cp = (const uint*)&(C_);                                 \
        const uint* Dp = (const uint*)&(D_);                                 \
        const uint* Wp = (const uint*)&dwv;                                  \
        _Pragma("unroll")                                                    \
        for (int j = 0; j < 4; ++j) {                                        \
            __half2 v = __hmul2(u2hh(Ap[j]), w00b);                          \
            v = __hfma2(u2hh(Bp[j]), w01b, v);                               \
            v = __hfma2(u2hh(Cp[j]), w10b, v);                               \
            v = __hfma2(u2hh(Dp[j]), w11b, v);                               \
            acc_h[j] = __hfma2(v, u2hh(Wp[j]), acc_h[j]);                    \
        }                                                                    \
    }

    uint id0 = sIdx[base];
    uint2 w40 = sW[base];
    uint id1; uint2 w41;
    uint4 A0, B0, C0, D0, A1, B1, C1, D1;
    CORNERS(id0, A0, B0, C0, D0);

    for (int t = 0; t + 1 < KK; t += 2) {
        id1 = sIdx[base + t + 1]; w41 = sW[base + t + 1];
        CORNERS(id1, A1, B1, C1, D1);
        MATH(t, A0, B0, C0, D0, w40);
        if (t + 2 < KK) {
            id0 = sIdx[base + t + 2]; w40 = sW[base + t + 2];
            CORNERS(id0, A0, B0, C0, D0);
        }
        MATH(t + 1, A1, B1, C1, D1, w41);
    }
    MATH(KK - 1, A0, B0, C0, D0, w40);   // KK odd: last tap in set 0

#undef CORNERS
#undef MATH

    uint o4[4];
    #pragma unroll
    for (int j = 0; j < 4; ++j) o4[j] = hh2u(acc_h[j]);
    *(uint4*)(outb + ((size_t)pix << 6) + gb) = *(uint4*)o4;
}

// ---------------------------------------------------------------------------
// Fused 1x1 conv (fp16 MFMA) + bias + u*attn. attn NHWC fp16; x/out NCHW f32.
// ---------------------------------------------------------------------------
__global__ __launch_bounds__(256) void pw_mfma(
    const ushort* __restrict__ attn, const ushort* __restrict__ wp2,
    const float* __restrict__ b1, const float* __restrict__ x,
    float* __restrict__ out) {
    __shared__ __align__(16) ushort lds[64 * 64];
    const int tid = threadIdx.x, lane = tid & 63, wid = tid >> 6;
    const int l15 = lane & 15, lg = lane >> 4;
    const int pix0 = blockIdx.x << 6;

    const uint4* src = (const uint4*)(attn + ((size_t)pix0 << 6));
    for (int q = tid; q < 512; q += 256) {
        const int widx = q >> 3, csl = q & 7;
        ((uint4*)lds)[widx * 8 + (csl ^ (widx & 7))] = src[q];
    }
    __syncthreads();

    const b16x8 a0 = *(const b16x8*)(wp2 + ((size_t)(wid * 16 + l15)) * 32 + lg * 8);
    const b16x8 a1 = *(const b16x8*)(wp2 + ((size_t)(64 + wid * 16 + l15)) * 32 + lg * 8);
    f32x4 acc[4] = {};
    #pragma unroll
    for (int pt = 0; pt < 4; ++pt) {
        const int wb = pt * 16 + l15;
        const int idx = wb * 8 + (lg ^ (wb & 7));
        const b16x8 b0 = ((const b16x8*)lds)[idx];
        const b16x8 b1v = ((const b16x8*)lds)[idx ^ 4];
        acc[pt] = __builtin_amdgcn_mfma_f32_16x16x32_f16(s2h8(a0), s2h8(b0), acc[pt], 0, 0, 0);
        acc[pt] = __builtin_amdgcn_mfma_f32_16x16x32_f16(s2h8(a1), s2h8(b1v), acc[pt], 0, 0, 0);
    }

    const int b = pix0 >> 14, hw0 = pix0 & 16383;
    #pragma unroll
    for (int r = 0; r < 4; ++r) {
        const int oc = wid * 16 + lg * 4 + r;
        const float bv = b1[oc];
        const size_t base = (((size_t)b * 64 + oc) << 14) + hw0;
        #pragma unroll
        for (int pt = 0; pt < 4; ++pt) {
            const size_t oi = base + pt * 16 + l15;
            out[oi] = x[oi] * (acc[pt][r] + bv);
        }
    }
}

extern "C" void kernel_launch(void* const* d_in, const int* in_sizes, int n_in,
                              void* d_out, int out_size, void* d_ws, size_t ws_size,
                              hipStream_t stream) {
    const float* x       = (const float*)d_in[0];
    const float* off0_w  = (const float*)d_in[1];
    const float* off0_b  = (const float*)d_in[2];
    const float* dw0_w   = (const float*)d_in[3];
    const float* off1_w  = (const float*)d_in[4];
    const float* off1_b  = (const float*)d_in[5];
    const float* dw1_w   = (const float*)d_in[6];
    const float* conv1_w = (const float*)d_in[7];
    const float* conv1_b = (const float*)d_in[8];
    float* out = (float*)d_out;

    const size_t NPX = (size_t)Bb * HW;
    ushort* xp     = (ushort*)d_ws;
    ushort* attn0b = xp + NPX * 64;
    ushort* attn1b = attn0b + NPX * 64;
    ushort* offb   = attn1b + NPX * 64;
    ushort* wp0    = offb + NPX * 98;
    ushort* wp1    = wp0 + 50 * 64 * 32;
    ushort* wpP    = wp1 + 98 * 112 * 32;
    ushort* dwt0   = wpP + 2 * 64 * 32;
    ushort* dwt1   = dwt0 + 25 * 64;

    const dim3 blk(256);

    pack_nhwc<<<2048, blk, 0, stream>>>(x, xp);
    pack_w<<<(50 * 64 * 32 + 255) / 256, blk, 0, stream>>>(off0_w, wp0, 50, 64, 25, 50 * 64 * 32);
    pack_w<<<(98 * 112 * 32 + 255) / 256, blk, 0, stream>>>(off1_w, wp1, 98, 112, 49, 98 * 112 * 32);
    pack_w<<<16, blk, 0, stream>>>(conv1_w, wpP, 64, 64, 1, 2 * 64 * 32);
    pack_dwt<<<(25 * 64 + 255) / 256, blk, 0, stream>>>(dw0_w, dwt0, 25);
    pack_dwt<<<(49 * 64 + 255) / 256, blk, 0, stream>>>(dw1_w, dwt1, 49);

    // Stage 1
    conv_mfma<5, 2, 1, 64, 2><<<1024, blk, 0, stream>>>(xp, wp0, off0_b, offb);
    deform5<5, 2, 1><<<4096, blk, 0, stream>>>(xp, offb, dwt0, attn0b);

    // Stage 2
    conv_mfma<7, 9, 3, 112, 2><<<1024, blk, 0, stream>>>(attn0b, wp1, off1_b, offb);
    deform5<7, 9, 3><<<4096, blk, 0, stream>>>(attn0b, offb, dwt1, attn1b);

    // Stage 3
    pw_mfma<<<2048, blk, 0, stream>>>(attn1b, wpP, conv1_b, x, out);
}